// Round 10
// baseline (359.882 us; speedup 1.0000x reference)
//
#include <hip/hip_runtime.h>

typedef __attribute__((ext_vector_type(8))) short short8;
typedef __attribute__((ext_vector_type(4))) short short4v;
typedef __attribute__((ext_vector_type(4))) float float4v;

#define NDIM 512
#define NN (NDIM*NDIM)
#define CD 128

__device__ __forceinline__ unsigned short f2b(float f) {
  union { float f; unsigned u; } v; v.f = f;
  unsigned r = v.u + 0x7FFFu + ((v.u >> 16) & 1u);
  return (unsigned short)(r >> 16);
}
__device__ __forceinline__ float b2f(unsigned short h) {
  union { unsigned u; float f; } v; v.u = ((unsigned)h) << 16; return v.f;
}
__device__ __forceinline__ float sigmoidf_(float x) { return 1.f / (1.f + __expf(-x)); }
// packed f32x2 -> bf16x2 (RNE), single VALU op
__device__ __forceinline__ unsigned pk2(float a, float b) {
  unsigned r;
  asm("v_cvt_pk_bf16_f32 %0, %1, %2" : "=v"(r) : "v"(a), "v"(b));
  return r;
}
__device__ __forceinline__ float4v mfma16(short8 a, short8 b, float4v c) {
  return __builtin_amdgcn_mfma_f32_16x16x32_bf16(a, b, c, 0, 0, 0);
}
__device__ __forceinline__ void gl_lds16(const short* g, short* l) {
  __builtin_amdgcn_global_load_lds(
      (const __attribute__((address_space(1))) unsigned int*)g,
      (__attribute__((address_space(3))) unsigned int*)l, 16, 0, 0);
}

// swizzled LDS tile, rows of 128 shorts (16 chunks of 16B), chunk ^= row&15
__device__ __forceinline__ short8 fragr(const short* buf, int row, int j) {
  return *(const short8*)(buf + row * 128 + ((j ^ (row & 15)) << 3));
}
// 4B write into the same swizzled layout: ku = uint index in [0,64)
__device__ __forceinline__ void stg_w(short* buf, int row, int ku, unsigned v) {
  *(unsigned*)&buf[row * 128 + ((((ku >> 2) ^ (row & 15)) << 3) + ((ku & 3) << 1))] = v;
}
// [ch][32-short] stage (a/b): 4 chunks/row, chunk ^= ch&3; ku = uint idx [0,16)
__device__ __forceinline__ short8 frag32(const short* buf, int ch, int j) {
  return *(const short8*)(buf + ch * 32 + ((j ^ (ch & 3)) << 3));
}
__device__ __forceinline__ void stg32(short* buf, int ch, int ku, unsigned v) {
  *(unsigned*)&buf[ch * 32 + ((((ku >> 2) ^ (ch & 3)) << 3) + ((ku & 3) << 1))] = v;
}
// [row][64-short] stage (g): 8 chunks/row, chunk ^= row&7; ku = uint idx [0,32)
__device__ __forceinline__ short8 frag64(const short* buf, int row, int j) {
  return *(const short8*)(buf + row * 64 + ((j ^ (row & 7)) << 3));
}
__device__ __forceinline__ void stg64(short* buf, int row, int ku, unsigned v) {
  *(unsigned*)&buf[row * 64 + ((((ku >> 2) ^ (row & 7)) << 3) + ((ku & 3) << 1))] = v;
}

// ---------------- kernel 0: weight prep f32 [k][n] -> bf16 [n][k] ----------------
__global__ __launch_bounds__(256) void kPrepW(
    const float* __restrict__ w0, const float* __restrict__ w1,
    const float* __restrict__ w2, const float* __restrict__ w3,
    const float* __restrict__ w4, short* __restrict__ wt)
{
  const int wi = blockIdx.y;
  const float* W = wi==0 ? w0 : wi==1 ? w1 : wi==2 ? w2 : wi==3 ? w3 : w4;
  const int e = blockIdx.x * 256 + threadIdx.x;   // 0..16383
  const int k = e >> 7, n = e & 127;              // coalesced read along n
  wt[wi * 16384 + n * 128 + k] = (short)f2b(W[k * CD + n]);
}

// ---------------- kernel 1: LN(z) + 5 projections + gating (v4) ----------------
// 4096 blocks x 256 thr; block = 64-channel half x (4 tiles x 32 rows).
// All 5 weight fragments in VGPRs; z prefetched to regs; zln double-buffered.
__global__ __launch_bounds__(256, 2) void kProj(
    const float* __restrict__ z, const float* __restrict__ mask,
    const short* __restrict__ wT,
    const float* __restrict__ b_a_p, const float* __restrict__ b_a_g,
    const float* __restrict__ b_b_p, const float* __restrict__ b_b_g,
    const float* __restrict__ b_g,
    const float* __restrict__ ln_s, const float* __restrict__ ln_b,
    short* __restrict__ a_t, short* __restrict__ b_t, short* __restrict__ g_out)
{
  __shared__ short zln[2][32 * 128]; // LN'd tile, double-buffered (swizzled)
  __shared__ short sSa[64 * 32];     // a stage [64 ch][32 rows]
  __shared__ short sSb[64 * 32];     // b stage
  __shared__ short sSg[32 * 64];     // g stage [32 rows][64 ch]

  const int tid = threadIdx.x;
  const int bid = blockIdx.x;
  const int sw = (bid & 7) * 512 + (bid >> 3);    // XCD swizzle (4096 % 8 == 0)
  const int ch_half = sw & 1;                     // z-sharing pair lands same XCD
  const int tg = sw >> 1;                         // 0..2047
  const int r0 = tg * 128;
  const int w = tid >> 6, l = tid & 63, lr = l & 15, lg = l >> 4;
  const int chw = ch_half * 64 + w * 16;          // wave's global channel base
  const int lrow = tid >> 3, q = tid & 7;         // LN mapping: 8 thr/row

  // ---- weight fragments -> VGPR (slots: 0=a_p 1=a_g 2=b_p 3=b_g 4=g) ----
  short8 wfr[5][4];
#pragma unroll
  for (int s = 0; s < 5; ++s)
#pragma unroll
    for (int ks = 0; ks < 4; ++ks)
      wfr[s][ks] = *(const short8*)(wT + s*16384 + (chw + lr)*128 + ks*32 + lg*8);

  const float bga = b_a_g[chw + lr], bpa = b_a_p[chw + lr];
  const float bgb = b_b_g[chw + lr], bpb = b_b_p[chw + lr];
  const float4v bgv = *(const float4v*)(b_g + chw + lg*4);

  const float* zbase = z + (size_t)(r0 + lrow) * CD + q * 16;
  float4v zrA[4], zrB[4];
#pragma unroll
  for (int i = 0; i < 4; ++i) zrA[i] = *(const float4v*)(zbase + i * 4);

#define WP2(ACC, WI) do {                                                   \
  ACC[0] = (float4v){0.f,0.f,0.f,0.f}; ACC[1] = (float4v){0.f,0.f,0.f,0.f}; \
  _Pragma("unroll") for (int ks_ = 0; ks_ < 4; ++ks_) {                     \
    ACC[0] = mfma16(af[0][ks_], wfr[WI][ks_], ACC[0]);                      \
    ACC[1] = mfma16(af[1][ks_], wfr[WI][ks_], ACC[1]); } } while(0)

#define PROJ_TILE(T, ZR, ZN) do {                                           \
  { /* LN of 32 rows from registers */                                      \
    float s_ = 0.f;                                                         \
    _Pragma("unroll") for (int i_ = 0; i_ < 4; ++i_)                        \
      s_ += ZR[i_][0] + ZR[i_][1] + ZR[i_][2] + ZR[i_][3];                  \
    s_ += __shfl_xor(s_, 1, 64); s_ += __shfl_xor(s_, 2, 64);               \
    s_ += __shfl_xor(s_, 4, 64);                                            \
    const float mu_ = s_ * (1.f/128.f);                                     \
    float vs_ = 0.f;                                                        \
    _Pragma("unroll") for (int i_ = 0; i_ < 16; ++i_) {                     \
      float d_ = ZR[i_>>2][i_&3] - mu_; vs_ += d_*d_; }                     \
    vs_ += __shfl_xor(vs_, 1, 64); vs_ += __shfl_xor(vs_, 2, 64);           \
    vs_ += __shfl_xor(vs_, 4, 64);                                          \
    const float rstd_ = rsqrtf(vs_ * (1.f/128.f) + 1e-5f);                  \
    union { unsigned u4[4]; short8 s8; } lo_, hi_;                          \
    _Pragma("unroll") for (int p_ = 0; p_ < 8; ++p_) {                      \
      int c_ = q*16 + p_*2;                                                 \
      float y0_ = (ZR[p_>>1][(p_&1)*2]   - mu_)*rstd_*ln_s[c_]   + ln_b[c_];     \
      float y1_ = (ZR[p_>>1][(p_&1)*2+1] - mu_)*rstd_*ln_s[c_+1] + ln_b[c_+1];   \
      if (p_ < 4) lo_.u4[p_] = pk2(y0_, y1_); else hi_.u4[p_-4] = pk2(y0_, y1_); \
    }                                                                       \
    short* zb_ = &zln[(T)&1][0];                                            \
    *(short8*)&zb_[lrow*128 + (((q*2)   ^ (lrow&15))<<3)] = lo_.s8;         \
    *(short8*)&zb_[lrow*128 + (((q*2+1) ^ (lrow&15))<<3)] = hi_.s8;         \
  }                                                                         \
  __syncthreads();  /* B1: zln[T&1] ready; prev tile stores drained */      \
  short8 af[2][4];                                                          \
  _Pragma("unroll") for (int rg_ = 0; rg_ < 2; ++rg_)                       \
    _Pragma("unroll") for (int ks_ = 0; ks_ < 4; ++ks_)                     \
      af[rg_][ks_] = fragr(&zln[(T)&1][0], rg_*16 + lr, ks_*4 + lg);        \
  float4v mr0 = *(const float4v*)(mask + r0 + (T)*32 + lg*4);               \
  float4v mr1 = *(const float4v*)(mask + r0 + (T)*32 + 16 + lg*4);          \
  if ((T) < 3) { /* prefetch next z tile; lands during passes */            \
    _Pragma("unroll") for (int i_ = 0; i_ < 4; ++i_)                        \
      ZN[i_] = *(const float4v*)(zbase + ((T)+1)*32*CD + i_*4);             \
  }                                                                         \
  float4v aG[2], aB[2];                                                     \
  /* ---- a: gate slot1, product slot0 ---- */                              \
  WP2(aG, 1); WP2(aB, 0);                                                   \
  _Pragma("unroll") for (int rg_ = 0; rg_ < 2; ++rg_) {                     \
    float4v mr_ = rg_ ? mr1 : mr0;                                          \
    float s0_ = sigmoidf_(aG[rg_][0]+bga)*mr_[0];                           \
    float s1_ = sigmoidf_(aG[rg_][1]+bga)*mr_[1];                           \
    float s2_ = sigmoidf_(aG[rg_][2]+bga)*mr_[2];                           \
    float s3_ = sigmoidf_(aG[rg_][3]+bga)*mr_[3];                           \
    stg32(sSa, w*16+lr, rg_*8+lg*2,                                         \
          pk2(s0_*(aB[rg_][0]+bpa), s1_*(aB[rg_][1]+bpa)));                 \
    stg32(sSa, w*16+lr, rg_*8+lg*2+1,                                       \
          pk2(s2_*(aB[rg_][2]+bpa), s3_*(aB[rg_][3]+bpa)));                 \
  }                                                                         \
  /* ---- b: gate slot3, product slot2 ---- */                              \
  WP2(aG, 3); WP2(aB, 2);                                                   \
  _Pragma("unroll") for (int rg_ = 0; rg_ < 2; ++rg_) {                     \
    float4v mr_ = rg_ ? mr1 : mr0;                                          \
    float s0_ = sigmoidf_(aG[rg_][0]+bgb)*mr_[0];                           \
    float s1_ = sigmoidf_(aG[rg_][1]+bgb)*mr_[1];                           \
    float s2_ = sigmoidf_(aG[rg_][2]+bgb)*mr_[2];                           \
    float s3_ = sigmoidf_(aG[rg_][3]+bgb)*mr_[3];                           \
    stg32(sSb, w*16+lr, rg_*8+lg*2,                                         \
          pk2(s0_*(aB[rg_][0]+bpb), s1_*(aB[rg_][1]+bpb)));                 \
    stg32(sSb, w*16+lr, rg_*8+lg*2+1,                                       \
          pk2(s2_*(aB[rg_][2]+bpb), s3_*(aB[rg_][3]+bpb)));                 \
  }                                                                         \
  /* ---- g: slot4, swapped operands (D row=channel, col=z-row) ---- */     \
  _Pragma("unroll") for (int rg_ = 0; rg_ < 2; ++rg_)                       \
    aG[rg_] = (float4v){0.f,0.f,0.f,0.f};                                   \
  _Pragma("unroll") for (int ks_ = 0; ks_ < 4; ++ks_) {                     \
    aG[0] = mfma16(wfr[4][ks_], af[0][ks_], aG[0]);                         \
    aG[1] = mfma16(wfr[4][ks_], af[1][ks_], aG[1]);                         \
  }                                                                         \
  _Pragma("unroll") for (int rg_ = 0; rg_ < 2; ++rg_) {                     \
    float g0_ = sigmoidf_(aG[rg_][0] + bgv[0]);                             \
    float g1_ = sigmoidf_(aG[rg_][1] + bgv[1]);                             \
    float g2_ = sigmoidf_(aG[rg_][2] + bgv[2]);                             \
    float g3_ = sigmoidf_(aG[rg_][3] + bgv[3]);                             \
    stg64(sSg, rg_*16+lr, w*8+lg*2,   pk2(g0_, g1_));                       \
    stg64(sSg, rg_*16+lr, w*8+lg*2+1, pk2(g2_, g3_));                       \
  }                                                                         \
  __syncthreads();  /* B2: sS* ready */                                     \
  { int chL_ = tid >> 2, jj_ = tid & 3;                                     \
    size_t go_ = (size_t)(ch_half*64 + chL_)*NN + r0 + (T)*32 + jj_*8;      \
    *(short8*)(a_t + go_) = frag32(sSa, chL_, jj_);                         \
    *(short8*)(b_t + go_) = frag32(sSb, chL_, jj_); }                       \
  { int rw_ = tid >> 3, jj_ = tid & 7;                                      \
    *(short8*)(g_out + (size_t)(r0 + (T)*32 + rw_)*CD + ch_half*64 + jj_*8) \
        = frag64(sSg, rw_, jj_); }                                          \
} while(0)

  PROJ_TILE(0, zrA, zrB);
  PROJ_TILE(1, zrB, zrA);
  PROJ_TILE(2, zrA, zrB);
  PROJ_TILE(3, zrB, zrA);
}

// ---------------- kernel 2: per-channel einsum GEMM X_c = A_c * B_c^T ----------------
__global__ __launch_bounds__(256, 2) void kEinsum(const short* __restrict__ a_t,
                                                  const short* __restrict__ b_t,
                                                  short* __restrict__ x_t)
{
  __shared__ short As[2][128 * 64];
  __shared__ short Bs[2][128 * 64];
  const int t = threadIdx.x;
  const int d = blockIdx.x;
  const int c = (d & 7) * 16 + (d >> 7);          // channel -> XCD grouping
  const int tile = (d >> 3) & 15;
  const int i0 = (tile >> 2) * 128;
  const int j0 = (tile & 3) * 128;
  const size_t abase = (size_t)c * NN;
  const int w = t >> 6, l = t & 63, lr = l & 15, lg = l >> 4;
  const int wr = w >> 1, wc = w & 1;

  const short* gA[4]; const short* gB[4]; int ldsU[4];
#pragma unroll
  for (int q = 0; q < 4; ++q) {
    int U = q * 256 + t;
    int row = U >> 3, u = U & 7;
    int swz = ((u ^ (row & 7)) << 3);
    gA[q] = a_t + abase + (size_t)(i0 + row) * NDIM + swz;
    gB[q] = b_t + abase + (size_t)(j0 + row) * NDIM + swz;
    ldsU[q] = U * 8;
  }

#define STAGE_E(buf, k0) do { _Pragma("unroll") for (int q_=0;q_<4;++q_) { \
    gl_lds16(gA[q_] + (k0), &As[buf][ldsU[q_]]);                           \
    gl_lds16(gB[q_] + (k0), &Bs[buf][ldsU[q_]]); } } while(0)

  float4v acc[4][4];
#pragma unroll
  for (int m = 0; m < 4; ++m)
#pragma unroll
    for (int n = 0; n < 4; ++n) acc[m][n] = (float4v){0.f,0.f,0.f,0.f};

  STAGE_E(0, 0);
  __syncthreads();
  int cur = 0;
#pragma unroll
  for (int it = 0; it < 8; ++it) {
    if (it < 7) STAGE_E(cur ^ 1, (it + 1) * 64);
    short8 afr[4][2], bfr[4][2];
#pragma unroll
    for (int m = 0; m < 4; ++m)
#pragma unroll
      for (int ks = 0; ks < 2; ++ks) {
        int row = wr*64 + m*16 + lr, j = ks*4 + lg;
        afr[m][ks] = *(const short8*)(&As[cur][row*64 + ((j ^ (row & 7)) << 3)]);
      }
#pragma unroll
    for (int n = 0; n < 4; ++n)
#pragma unroll
      for (int ks = 0; ks < 2; ++ks) {
        int row = wc*64 + n*16 + lr, j = ks*4 + lg;
        bfr[n][ks] = *(const short8*)(&Bs[cur][row*64 + ((j ^ (row & 7)) << 3)]);
      }
    __builtin_amdgcn_s_setprio(1);
#pragma unroll
    for (int ks = 0; ks < 2; ++ks)
#pragma unroll
      for (int m = 0; m < 4; ++m)
#pragma unroll
        for (int n = 0; n < 4; ++n)   // swapped: D = (j, i)
          acc[m][n] = mfma16(bfr[n][ks], afr[m][ks], acc[m][n]);
    __builtin_amdgcn_s_setprio(0);
    __syncthreads();
    cur ^= 1;
  }
  // epilogue: stage x-tile into As region (swizzled), then 128B/thread stores
  short* Xs = &As[0][0];                          // 128 x 128 shorts = 32KB
#pragma unroll
  for (int m = 0; m < 4; ++m)
#pragma unroll
    for (int n = 0; n < 4; ++n) {
      int il = wr*64 + m*16 + lr;
      int ku = wc*32 + n*8 + lg*2;
      stg_w(Xs, il, ku,   pk2(acc[m][n][0], acc[m][n][1]));
      stg_w(Xs, il, ku+1, pk2(acc[m][n][2], acc[m][n][3]));
    }
  __syncthreads();
#pragma unroll
  for (int i = 0; i < 8; ++i) {
    int il = t >> 1, cL = (t & 1)*8 + i;
    *(short8*)(x_t + abase + (size_t)(i0 + il)*NDIM + j0 + cL*8) = fragr(Xs, il, cL);
  }
}

// ---------------- kernel 3: LN(x) + x@w_z + b_z, * gate ----------------
__global__ __launch_bounds__(256, 2) void kOut(
    const short* __restrict__ x_t, const short* __restrict__ g_in,
    const float* __restrict__ w_z, const float* __restrict__ b_z,
    const float* __restrict__ ln_s, const float* __restrict__ ln_b,
    float* __restrict__ out)
{
  __shared__ short xs[128 * 72];    // gathered x [c][r], swizzled r-chunks
  __shared__ short xln[64 * 128];   // swizzled
  __shared__ short sW[128 * 128];   // swizzled w_z; f32 out-stage at end
  const int t = threadIdx.x;
  const int r0 = blockIdx.x * 64;
  const int w = t >> 6, l = t & 63, lr = l & 15, lg = l >> 4;

  // A) stage w_z f32 [k][n] -> swizzled bf16 [n][k]
#pragma unroll
  for (int i = 0; i < 8; ++i) {
    int flat = i * 256 + t;
    int kp = flat >> 5, k = kp * 2, n4 = (flat & 31) * 4;
    float4v va = *(const float4v*)(w_z + (size_t)k * CD + n4);
    float4v vb = *(const float4v*)(w_z + (size_t)(k + 1) * CD + n4);
#pragma unroll
    for (int j = 0; j < 4; ++j) {
      int row = n4 + j;
      int addr = row * 128 + (((k >> 3) ^ (row & 15)) << 3) + (k & 7);
      *(unsigned*)(&sW[addr]) = pk2(va[j], vb[j]);
    }
  }
  // B) gather x columns -> xs
#pragma unroll
  for (int it = 0; it < 4; ++it) {
    int v = it * 256 + t; int cc = v >> 3; int u = v & 7;
    int up = u ^ ((cc >> 3) & 7);
    *(short8*)&xs[cc * 72 + up * 8] = *(const short8*)(x_t + (size_t)cc * NN + r0 + u * 8);
  }
  __syncthreads();                                // s1
  // C) LN over channels
  {
    const int r = t >> 2, q = t & 3;
    float x[32];
#pragma unroll
    for (int i = 0; i < 32; ++i) {
      int c = q * 32 + i;
      x[i] = b2f((unsigned short)xs[c * 72 + (((r >> 3) ^ ((c >> 3) & 7)) << 3) + (r & 7)]);
    }
    float s = 0.f;
#pragma unroll
    for (int i = 0; i < 32; ++i) s += x[i];
    s += __shfl_xor(s, 1, 64);
    s += __shfl_xor(s, 2, 64);
    const float mu = s * (1.f/128.f);
    float vs = 0.f;
#pragma unroll
    for (int i = 0; i < 32; ++i) { float d = x[i]-mu; vs += d*d; }
    vs += __shfl_xor(vs, 1, 64);
    vs += __shfl_xor(vs, 2, 64);
    const float rstd = rsqrtf(vs * (1.f/128.f) + 1e-5f);
#pragma unroll
    for (int i = 0; i < 32; ++i) {
      int c = q*32 + i;
      float y = (x[i]-mu)*rstd*ln_s[c] + ln_b[c];
      xln[r*128 + (((c>>3) ^ (r & 15)) << 3) + (c & 7)] = (short)f2b(y);
    }
  }
  __syncthreads();                                // s2
  short8 af[4];
#pragma unroll
  for (int ks = 0; ks < 4; ++ks)
    af[ks] = fragr(xln, w*16 + lr, ks*4 + lg);

  // D) swapped final mfma: D = (channel, row)
  float4v acc[8];
#pragma unroll
  for (int cf = 0; cf < 8; ++cf) acc[cf] = (float4v){0.f,0.f,0.f,0.f};
#pragma unroll
  for (int ks = 0; ks < 4; ++ks)
#pragma unroll
    for (int cf = 0; cf < 8; ++cf) {
      short8 wf = fragr(sW, cf*16 + lr, ks*4 + lg);
      acc[cf] = mfma16(wf, af[ks], acc[cf]);
    }
  __syncthreads();                                // s3: sW reads done -> reuse as f32 stage
  float* fWs = (float*)sW;                        // [64 rows][128 c] f32, chunk-swizzled
  const int orow = r0 + w*16 + lr;
  const int rl = w*16 + lr;
#pragma unroll
  for (int cf = 0; cf < 8; ++cf) {
    float4v bzv = *(const float4v*)(b_z + cf*16 + lg*4);
    short4v gv = *(const short4v*)(g_in + (size_t)orow * CD + cf*16 + lg*4);
    float4v o;
#pragma unroll
    for (int j = 0; j < 4; ++j)
      o[j] = (acc[cf][j] + bzv[j]) * b2f((unsigned short)gv[j]);
    *(float4v*)&fWs[rl*128 + (((cf*4+lg) ^ (rl & 15)) << 2)] = o;
  }
  __syncthreads();                                // s4
#pragma unroll
  for (int i = 0; i < 8; ++i) {                   // 512B contiguous per row
    int row = t >> 2, cL = (t & 3)*8 + i;
    *(float4v*)(out + (size_t)(r0 + row)*CD + cL*4) =
        *(const float4v*)&fWs[row*128 + ((cL ^ (row & 15)) << 2)];
  }
}

extern "C" void kernel_launch(void* const* d_in, const int* in_sizes, int n_in,
                              void* d_out, int out_size, void* d_ws, size_t ws_size,
                              hipStream_t stream) {
  (void)in_sizes; (void)n_in; (void)out_size; (void)ws_size;
  const float* z     = (const float*)d_in[0];
  const float* mask  = (const float*)d_in[1];
  const float* w_a_p = (const float*)d_in[2];
  const float* b_a_p = (const float*)d_in[3];
  const float* w_a_g = (const float*)d_in[4];
  const float* b_a_g = (const float*)d_in[5];
  const float* w_b_p = (const float*)d_in[6];
  const float* b_b_p = (const float*)d_in[7];
  const float* w_b_g = (const float*)d_in[8];
  const float* b_b_g = (const float*)d_in[9];
  const float* w_g   = (const float*)d_in[10];
  const float* b_g   = (const float*)d_in[11];
  const float* w_z   = (const float*)d_in[12];
  const float* b_z   = (const float*)d_in[13];
  const float* ln_i_s = (const float*)d_in[14];
  const float* ln_i_b = (const float*)d_in[15];
  const float* ln_o_s = (const float*)d_in[16];
  const float* ln_o_b = (const float*)d_in[17];

  short* a_t = (short*)d_ws;
  short* b_t = a_t + (size_t)CD*NN;
  short* g_s = b_t + (size_t)CD*NN;
  short* x_t = g_s + (size_t)CD*NN;
  short* wT  = x_t;                                // 160 KB at head of x_t (kProj only)

  hipLaunchKernelGGL(kPrepW, dim3(64, 5), dim3(256), 0, stream,
                     w_a_p, w_a_g, w_b_p, w_b_g, w_g, wT);
  hipLaunchKernelGGL(kProj, dim3(4096), dim3(256), 0, stream,
                     z, mask, wT, b_a_p, b_a_g, b_b_p, b_b_g, b_g,
                     ln_i_s, ln_i_b, a_t, b_t, g_s);
  hipLaunchKernelGGL(kEinsum, dim3(2048), dim3(256), 0, stream, a_t, b_t, x_t);
  hipLaunchKernelGGL(kOut, dim3(NN/64), dim3(256), 0, stream,
                     x_t, g_s, w_z, b_z, ln_o_s, ln_o_b, (float*)d_out);
}

// Round 11
// 346.673 us; speedup vs baseline: 1.0381x; 1.0381x over previous
//
#include <hip/hip_runtime.h>

typedef __attribute__((ext_vector_type(8))) short short8;
typedef __attribute__((ext_vector_type(4))) short short4v;
typedef __attribute__((ext_vector_type(4))) float float4v;

#define NDIM 512
#define NN (NDIM*NDIM)
#define CD 128

__device__ __forceinline__ unsigned short f2b(float f) {
  union { float f; unsigned u; } v; v.f = f;
  unsigned r = v.u + 0x7FFFu + ((v.u >> 16) & 1u);
  return (unsigned short)(r >> 16);
}
__device__ __forceinline__ float b2f(unsigned short h) {
  union { unsigned u; float f; } v; v.u = ((unsigned)h) << 16; return v.f;
}
__device__ __forceinline__ float sigmoidf_(float x) { return 1.f / (1.f + __expf(-x)); }
// packed f32x2 -> bf16x2 (RNE), single VALU op
__device__ __forceinline__ unsigned pk2(float a, float b) {
  unsigned r;
  asm("v_cvt_pk_bf16_f32 %0, %1, %2" : "=v"(r) : "v"(a), "v"(b));
  return r;
}
__device__ __forceinline__ float4v mfma16(short8 a, short8 b, float4v c) {
  return __builtin_amdgcn_mfma_f32_16x16x32_bf16(a, b, c, 0, 0, 0);
}
__device__ __forceinline__ void gl_lds16(const short* g, short* l) {
  __builtin_amdgcn_global_load_lds(
      (const __attribute__((address_space(1))) unsigned int*)g,
      (__attribute__((address_space(3))) unsigned int*)l, 16, 0, 0);
}

// swizzled LDS tile, rows of 128 shorts (16 chunks of 16B), chunk ^= row&15
__device__ __forceinline__ short8 fragr(const short* buf, int row, int j) {
  return *(const short8*)(buf + row * 128 + ((j ^ (row & 15)) << 3));
}
// 4B write into the same swizzled layout: ku = uint index in [0,64)
__device__ __forceinline__ void stg_w(short* buf, int row, int ku, unsigned v) {
  *(unsigned*)&buf[row * 128 + ((((ku >> 2) ^ (row & 15)) << 3) + ((ku & 3) << 1))] = v;
}

// ---------------- kernel 0: weight prep f32 [k][n] -> bf16 [n][k] ----------------
__global__ __launch_bounds__(256) void kPrepW(
    const float* __restrict__ w0, const float* __restrict__ w1,
    const float* __restrict__ w2, const float* __restrict__ w3,
    const float* __restrict__ w4, short* __restrict__ wt)
{
  const int wi = blockIdx.y;
  const float* W = wi==0 ? w0 : wi==1 ? w1 : wi==2 ? w2 : wi==3 ? w3 : w4;
  const int e = blockIdx.x * 256 + threadIdx.x;   // 0..16383
  const int k = e >> 7, n = e & 127;              // coalesced read along n
  wt[wi * 16384 + n * 128 + k] = (short)f2b(W[k * CD + n]);
}

// ---------------- kernel 1: LN(z) + 5 projections + gating ----------------
// 2048 blocks x 1024 thr; block = 128 rows; wave = 16 rows x 64 channels.
// (r9 known-good: 190 us, absmax 0.03125)
__global__ __launch_bounds__(1024, 4) void kProj(
    const float* __restrict__ z, const float* __restrict__ mask,
    const short* __restrict__ wT,
    const float* __restrict__ b_a_p, const float* __restrict__ b_a_g,
    const float* __restrict__ b_b_p, const float* __restrict__ b_b_g,
    const float* __restrict__ b_g,
    const float* __restrict__ ln_s, const float* __restrict__ ln_b,
    short* __restrict__ a_t, short* __restrict__ b_t, short* __restrict__ g_out)
{
  __shared__ short zln[128 * 128];   // LN result, never overwritten
  __shared__ short sS[128 * 128];    // av/bv [128 ch][128 rows], then gv [128 rows][128 ch]
  __shared__ short wA[128 * 128];    // gate-weight buffer
  __shared__ short wB[128 * 128];    // product-weight buffer
  const int t = threadIdx.x;
  const int r0 = blockIdx.x * 128;
  const int w = t >> 6, l = t & 63, lr = l & 15, lg = l >> 4;
  const int wr = (w >> 1) * 16;      // wave row base within block (0..112)
  const int hc = (w & 1) * 64;       // wave channel-half base

#define STAGE2(BUF, SLOT) do { _Pragma("unroll") for (int i_=0;i_<2;++i_) {  \
    int U_ = i_*1024 + t; int row_ = U_ >> 4, u_ = U_ & 15;                  \
    gl_lds16(wT + (SLOT)*16384 + row_*128 + ((u_^(row_&15))<<3), (BUF)+U_*8); } } while(0)

  STAGE2(wA, 1);                                  // w_a_g
  STAGE2(wB, 0);                                  // w_a_p

  // ---- LN: 8 threads/row, 16 f32 each, 128 rows ----
  {
    const int row = t >> 3, q = t & 7;
    const float* zp = z + (size_t)(r0 + row) * CD + q * 16;
    float x[16];
#pragma unroll
    for (int i = 0; i < 4; ++i) {
      float4v v = *(const float4v*)(zp + i * 4);
#pragma unroll
      for (int e = 0; e < 4; ++e) x[i*4+e] = v[e];
    }
    float s = 0.f;
#pragma unroll
    for (int i = 0; i < 16; ++i) s += x[i];
    s += __shfl_xor(s, 1, 64);
    s += __shfl_xor(s, 2, 64);
    s += __shfl_xor(s, 4, 64);
    const float mu = s * (1.f/128.f);
    float vs = 0.f;
#pragma unroll
    for (int i = 0; i < 16; ++i) { float d = x[i]-mu; vs += d*d; }
    vs += __shfl_xor(vs, 1, 64);
    vs += __shfl_xor(vs, 2, 64);
    vs += __shfl_xor(vs, 4, 64);
    const float rstd = rsqrtf(vs * (1.f/128.f) + 1e-5f);
#pragma unroll
    for (int i = 0; i < 16; i += 2) {
      int c = q*16 + i;
      float y0 = (x[i]  -mu)*rstd*ln_s[c]   + ln_b[c];
      float y1 = (x[i+1]-mu)*rstd*ln_s[c+1] + ln_b[c+1];
      int addr = row*128 + (((c>>3) ^ (row & 15)) << 3) + (c & 7);
      *(unsigned*)(&zln[addr]) = pk2(y0, y1);
    }
  }

  float bga[4], bpa[4], bgb[4], bpb[4];
#pragma unroll
  for (int cf = 0; cf < 4; ++cf) {
    int ci = hc + cf*16 + lr;
    bga[cf] = b_a_g[ci]; bpa[cf] = b_a_p[ci];
    bgb[cf] = b_b_g[ci]; bpb[cf] = b_b_p[ci];
  }
  float mrow[4];
#pragma unroll
  for (int jj = 0; jj < 4; ++jj) mrow[jj] = mask[r0 + wr + lg*4 + jj];

  __syncthreads();                                // B1: zln + wA + wB ready

  short8 af[4];
#pragma unroll
  for (int ks = 0; ks < 4; ++ks)
    af[ks] = fragr(zln, wr + lr, ks*4 + lg);

  float4v accG[4], accB[4];
  float sg[4][4];

#define ZERO4(A) do { _Pragma("unroll") for (int c_=0;c_<4;++c_) A[c_] = (float4v){0.f,0.f,0.f,0.f}; } while(0)

  // 16-MFMA pass: acc[cf] += af[ks] x BUF[hc+cf*16+lr]  (D: row=z-row, col=channel)
#define WP(ACC, BUF) do { ZERO4(ACC);                                      \
  _Pragma("unroll") for (int ks_=0; ks_<4; ++ks_)                          \
    _Pragma("unroll") for (int cf_=0; cf_<4; ++cf_) {                      \
      short8 wf_ = fragr(BUF, hc + cf_*16 + lr, ks_*4 + lg);               \
      ACC[cf_] = mfma16(af[ks_], wf_, ACC[cf_]);                           \
    } } while(0)

#define SIG4(BG) do { _Pragma("unroll") for (int cf_=0;cf_<4;++cf_)        \
    _Pragma("unroll") for (int j_=0;j_<4;++j_)                             \
      sg[cf_][j_] = sigmoidf_(accG[cf_][j_] + BG[cf_]) * mrow[j_]; } while(0)

  // pack sg*(accB+bias) -> sS ch-major: LDS row = channel, uint 2*ku = z-row offset
#define PKAB(BP) do { _Pragma("unroll") for (int cf_=0;cf_<4;++cf_) {      \
    float v0_ = sg[cf_][0]*(accB[cf_][0]+BP[cf_]);                         \
    float v1_ = sg[cf_][1]*(accB[cf_][1]+BP[cf_]);                         \
    float v2_ = sg[cf_][2]*(accB[cf_][2]+BP[cf_]);                         \
    float v3_ = sg[cf_][3]*(accB[cf_][3]+BP[cf_]);                         \
    int ch_ = hc + cf_*16 + lr, ku_ = (wr >> 1) + lg*2;                    \
    stg_w(sS, ch_, ku_,   pk2(v0_, v1_));                                  \
    stg_w(sS, ch_, ku_+1, pk2(v2_, v3_)); } } while(0)

  // full-sector store of sS [128 ch][128 rows] to DST[ch][r0..r0+128): 32B/thread
#define STORE64A(DST) do { int ch_ = t >> 3;                               \
  _Pragma("unroll") for (int i_=0;i_<2;++i_) {                             \
    int cL_ = (t & 7)*2 + i_;                                              \
    *(short8*)(DST + (size_t)ch_*NN + r0 + cL_*8) = fragr(sS, ch_, cL_);   \
  } } while(0)

  // S1: both a-projections
  WP(accG, wA);                                   // a_g
  WP(accB, wB);                                   // a_p
  SIG4(bga);
  PKAB(bpa);                                      // av -> sS
  __syncthreads();                                // B2: weight reads + av writes done

  // S2: restage weights; store a
  STAGE2(wA, 3);                                  // w_b_g
  STAGE2(wB, 2);                                  // w_b_p
  STORE64A(a_t);
  __syncthreads();                                // B3: stages drained; sS reads done

  // S3: both b-projections
  WP(accG, wA);                                   // b_g
  WP(accB, wB);                                   // b_p
  SIG4(bgb);
  PKAB(bpb);                                      // bv -> sS
  __syncthreads();                                // B4

  // S4: stage w_g; store b
  STAGE2(wA, 4);                                  // w_g
  STORE64A(b_t);
  __syncthreads();                                // B5: w_g ready; sS reads done

  // S5: gate projection (swapped: D row=channel, col=z-row), gv -> sS row-major
  {
    float4v accG2[4];
    ZERO4(accG2);
#pragma unroll
    for (int ks = 0; ks < 4; ++ks)
#pragma unroll
      for (int cf = 0; cf < 4; ++cf) {
        short8 wf = fragr(wA, hc + cf*16 + lr, ks*4 + lg);
        accG2[cf] = mfma16(wf, af[ks], accG2[cf]);
      }
#pragma unroll
    for (int cf = 0; cf < 4; ++cf) {
      float4v bgv = *(const float4v*)(b_g + hc + cf*16 + lg*4);
      float v0 = sigmoidf_(accG2[cf][0] + bgv[0]);
      float v1 = sigmoidf_(accG2[cf][1] + bgv[1]);
      float v2 = sigmoidf_(accG2[cf][2] + bgv[2]);
      float v3 = sigmoidf_(accG2[cf][3] + bgv[3]);
      int row = wr + lr, ku = (hc >> 1) + cf*8 + lg*2;
      stg_w(sS, row, ku,   pk2(v0, v1));
      stg_w(sS, row, ku+1, pk2(v2, v3));
    }
  }
  __syncthreads();                                // B6

  // S6: store g (row-major, 256B contiguous per row)
  {
    int row = t >> 3;
#pragma unroll
    for (int i = 0; i < 2; ++i) {
      int cL = (t & 7)*2 + i;
      *(short8*)(g_out + (size_t)(r0 + row)*CD + cL*8) = fragr(sS, row, cL);
    }
  }
}

// ---------------- kernel 2: per-channel einsum GEMM X_c = A_c * B_c^T ----------------
// Counted-vmcnt pipeline: next tile's 8 global_load_lds stay in flight across
// barriers (T3/T4); vmcnt(0) only on the last iteration.
__global__ __launch_bounds__(256, 2) void kEinsum(const short* __restrict__ a_t,
                                                  const short* __restrict__ b_t,
                                                  short* __restrict__ x_t)
{
  __shared__ short As[2][128 * 64];
  __shared__ short Bs[2][128 * 64];
  const int t = threadIdx.x;
  const int d = blockIdx.x;
  const int c = (d & 7) * 16 + (d >> 7);          // channel -> XCD grouping
  const int tile = (d >> 3) & 15;
  const int i0 = (tile >> 2) * 128;
  const int j0 = (tile & 3) * 128;
  const size_t abase = (size_t)c * NN;
  const int w = t >> 6, l = t & 63, lr = l & 15, lg = l >> 4;
  const int wr = w >> 1, wc = w & 1;

  const short* gA[4]; const short* gB[4]; int ldsU[4];
#pragma unroll
  for (int q = 0; q < 4; ++q) {
    int U = q * 256 + t;
    int row = U >> 3, u = U & 7;
    int swz = ((u ^ (row & 7)) << 3);
    gA[q] = a_t + abase + (size_t)(i0 + row) * NDIM + swz;
    gB[q] = b_t + abase + (size_t)(j0 + row) * NDIM + swz;
    ldsU[q] = U * 8;
  }

#define STAGE_E(buf, k0) do { _Pragma("unroll") for (int q_=0;q_<4;++q_) { \
    gl_lds16(gA[q_] + (k0), &As[buf][ldsU[q_]]);                           \
    gl_lds16(gB[q_] + (k0), &Bs[buf][ldsU[q_]]); } } while(0)

  float4v acc[4][4];
#pragma unroll
  for (int m = 0; m < 4; ++m)
#pragma unroll
    for (int n = 0; n < 4; ++n) acc[m][n] = (float4v){0.f,0.f,0.f,0.f};

  STAGE_E(0, 0);                                  // tile 0 -> buf 0
  STAGE_E(1, 64);                                 // tile 1 -> buf 1 (16 in flight)
#pragma unroll
  for (int it = 0; it < 8; ++it) {
    // wait for current tile's 8 loads; keep next tile's 8 in flight
    if (it < 7) asm volatile("s_waitcnt vmcnt(8)" ::: "memory");
    else        asm volatile("s_waitcnt vmcnt(0)" ::: "memory");
    __builtin_amdgcn_sched_barrier(0);
    __builtin_amdgcn_s_barrier();                 // all waves: buf[it&1] complete
    const short* Ab = &As[it & 1][0];
    const short* Bb = &Bs[it & 1][0];
    short8 afr[4][2], bfr[4][2];
#pragma unroll
    for (int m = 0; m < 4; ++m)
#pragma unroll
      for (int ks = 0; ks < 2; ++ks) {
        int row = wr*64 + m*16 + lr, j = ks*4 + lg;
        afr[m][ks] = *(const short8*)(Ab + row*64 + ((j ^ (row & 7)) << 3));
      }
#pragma unroll
    for (int n = 0; n < 4; ++n)
#pragma unroll
      for (int ks = 0; ks < 2; ++ks) {
        int row = wc*64 + n*16 + lr, j = ks*4 + lg;
        bfr[n][ks] = *(const short8*)(Bb + row*64 + ((j ^ (row & 7)) << 3));
      }
    __builtin_amdgcn_s_setprio(1);
#pragma unroll
    for (int ks = 0; ks < 2; ++ks)
#pragma unroll
      for (int m = 0; m < 4; ++m)
#pragma unroll
        for (int n = 0; n < 4; ++n)   // swapped: D = (j, i)
          acc[m][n] = mfma16(bfr[n][ks], afr[m][ks], acc[m][n]);
    __builtin_amdgcn_s_setprio(0);
    __builtin_amdgcn_s_barrier();                 // all waves done reading buf[it&1]
    __builtin_amdgcn_sched_barrier(0);
    if (it < 6) STAGE_E(it & 1, (it + 2) * 64);   // refill freed buffer
  }
  // epilogue: stage x-tile into As region (swizzled), then 128B/thread stores
  short* Xs = &As[0][0];                          // 128 x 128 shorts = 32KB
#pragma unroll
  for (int m = 0; m < 4; ++m)
#pragma unroll
    for (int n = 0; n < 4; ++n) {
      int il = wr*64 + m*16 + lr;
      int ku = wc*32 + n*8 + lg*2;
      stg_w(Xs, il, ku,   pk2(acc[m][n][0], acc[m][n][1]));
      stg_w(Xs, il, ku+1, pk2(acc[m][n][2], acc[m][n][3]));
    }
  __syncthreads();
#pragma unroll
  for (int i = 0; i < 8; ++i) {
    int il = t >> 1, cL = (t & 1)*8 + i;
    *(short8*)(x_t + abase + (size_t)(i0 + il)*NDIM + j0 + cL*8) = fragr(Xs, il, cL);
  }
}

// ---------------- kernel 3: LN(x) + x@w_z + b_z, * gate ----------------
__global__ __launch_bounds__(256, 2) void kOut(
    const short* __restrict__ x_t, const short* __restrict__ g_in,
    const float* __restrict__ w_z, const float* __restrict__ b_z,
    const float* __restrict__ ln_s, const float* __restrict__ ln_b,
    float* __restrict__ out)
{
  __shared__ short xs[128 * 72];    // gathered x [c][r], swizzled r-chunks
  __shared__ short xln[64 * 128];   // swizzled
  __shared__ short sW[128 * 128];   // swizzled w_z; f32 out-stage at end
  const int t = threadIdx.x;
  const int r0 = blockIdx.x * 64;
  const int w = t >> 6, l = t & 63, lr = l & 15, lg = l >> 4;

  // A) stage w_z f32 [k][n] -> swizzled bf16 [n][k]
#pragma unroll
  for (int i = 0; i < 8; ++i) {
    int flat = i * 256 + t;
    int kp = flat >> 5, k = kp * 2, n4 = (flat & 31) * 4;
    float4v va = *(const float4v*)(w_z + (size_t)k * CD + n4);
    float4v vb = *(const float4v*)(w_z + (size_t)(k + 1) * CD + n4);
#pragma unroll
    for (int j = 0; j < 4; ++j) {
      int row = n4 + j;
      int addr = row * 128 + (((k >> 3) ^ (row & 15)) << 3) + (k & 7);
      *(unsigned*)(&sW[addr]) = pk2(va[j], vb[j]);
    }
  }
  // B) gather x columns -> xs
#pragma unroll
  for (int it = 0; it < 4; ++it) {
    int v = it * 256 + t; int cc = v >> 3; int u = v & 7;
    int up = u ^ ((cc >> 3) & 7);
    *(short8*)&xs[cc * 72 + up * 8] = *(const short8*)(x_t + (size_t)cc * NN + r0 + u * 8);
  }
  __syncthreads();                                // s1
  // C) LN over channels
  {
    const int r = t >> 2, q = t & 3;
    float x[32];
#pragma unroll
    for (int i = 0; i < 32; ++i) {
      int c = q * 32 + i;
      x[i] = b2f((unsigned short)xs[c * 72 + (((r >> 3) ^ ((c >> 3) & 7)) << 3) + (r & 7)]);
    }
    float s = 0.f;
#pragma unroll
    for (int i = 0; i < 32; ++i) s += x[i];
    s += __shfl_xor(s, 1, 64);
    s += __shfl_xor(s, 2, 64);
    const float mu = s * (1.f/128.f);
    float vs = 0.f;
#pragma unroll
    for (int i = 0; i < 32; ++i) { float d = x[i]-mu; vs += d*d; }
    vs += __shfl_xor(vs, 1, 64);
    vs += __shfl_xor(vs, 2, 64);
    const float rstd = rsqrtf(vs * (1.f/128.f) + 1e-5f);
#pragma unroll
    for (int i = 0; i < 32; ++i) {
      int c = q*32 + i;
      float y = (x[i]-mu)*rstd*ln_s[c] + ln_b[c];
      xln[r*128 + (((c>>3) ^ (r & 15)) << 3) + (c & 7)] = (short)f2b(y);
    }
  }
  __syncthreads();                                // s2
  short8 af[4];
#pragma unroll
  for (int ks = 0; ks < 4; ++ks)
    af[ks] = fragr(xln, w*16 + lr, ks*4 + lg);

  // D) swapped final mfma: D = (channel, row)
  float4v acc[8];
#pragma unroll
  for (int cf = 0; cf < 8; ++cf) acc[cf] = (float4v){0.f,0.f,0.f,0.f};
#pragma unroll
  for (int ks = 0; ks < 4; ++ks)
#pragma unroll
    for (int cf = 0; cf < 8; ++cf) {
      short8 wf = fragr(sW, cf*16 + lr, ks*4 + lg);
      acc[cf] = mfma16(wf, af[ks], acc[cf]);
    }
  __syncthreads();                                // s3: sW reads done -> reuse as f32 stage
  float* fWs = (float*)sW;                        // [64 rows][128 c] f32, chunk-swizzled
  const int orow = r0 + w*16 + lr;
  const int rl = w*16 + lr;
#pragma unroll
  for (int cf = 0; cf < 8; ++cf) {
    float4v bzv = *(const float4v*)(b_z + cf*16 + lg*4);
    short4v gv = *(const short4v*)(g_in + (size_t)orow * CD + cf*16 + lg*4);
    float4v o;
#pragma unroll
    for (int j = 0; j < 4; ++j)
      o[j] = (acc[cf][j] + bzv[j]) * b2f((unsigned short)gv[j]);
    *(float4v*)&fWs[rl*128 + (((cf*4+lg) ^ (rl & 15)) << 2)] = o;
  }
  __syncthreads();                                // s4
#pragma unroll
  for (int i = 0; i < 8; ++i) {                   // 512B contiguous per row
    int row = t >> 2, cL = (t & 3)*8 + i;
    *(float4v*)(out + (size_t)(r0 + row)*CD + cL*4) =
        *(const float4v*)&fWs[row*128 + ((cL ^ (row & 15)) << 2)];
  }
}

extern "C" void kernel_launch(void* const* d_in, const int* in_sizes, int n_in,
                              void* d_out, int out_size, void* d_ws, size_t ws_size,
                              hipStream_t stream) {
  (void)in_sizes; (void)n_in; (void)out_size; (void)ws_size;
  const float* z     = (const float*)d_in[0];
  const float* mask  = (const float*)d_in[1];
  const float* w_a_p = (const float*)d_in[2];
  const float* b_a_p = (const float*)d_in[3];
  const float* w_a_g = (const float*)d_in[4];
  const float* b_a_g = (const float*)d_in[5];
  const float* w_b_p = (const float*)d_in[6];
  const float* b_b_p = (const float*)d_in[7];
  const float* w_b_g = (const float*)d_in[8];
  const float* b_b_g = (const float*)d_in[9];
  const float* w_g   = (const float*)d_in[10];
  const float* b_g   = (const float*)d_in[11];
  const float* w_z   = (const float*)d_in[12];
  const float* b_z   = (const float*)d_in[13];
  const float* ln_i_s = (const float*)d_in[14];
  const float* ln_i_b = (const float*)d_in[15];
  const float* ln_o_s = (const float*)d_in[16];
  const float* ln_o_b = (const float*)d_in[17];

  short* a_t = (short*)d_ws;
  short* b_t = a_t + (size_t)CD*NN;
  short* g_s = b_t + (size_t)CD*NN;
  short* x_t = g_s + (size_t)CD*NN;
  short* wT  = x_t;                                // 160 KB at head of x_t (kProj only)

  hipLaunchKernelGGL(kPrepW, dim3(64, 5), dim3(256), 0, stream,
                     w_a_p, w_a_g, w_b_p, w_b_g, w_g, wT);
  hipLaunchKernelGGL(kProj, dim3(NN/128), dim3(1024), 0, stream,
                     z, mask, wT, b_a_p, b_a_g, b_b_p, b_b_g, b_g,
                     ln_i_s, ln_i_b, a_t, b_t, g_s);
  hipLaunchKernelGGL(kEinsum, dim3(2048), dim3(256), 0, stream, a_t, b_t, x_t);
  hipLaunchKernelGGL(kOut, dim3(NN/64), dim3(256), 0, stream,
                     x_t, g_s, w_z, b_z, ln_o_s, ln_o_b, (float*)d_out);
}

// Round 12
// 312.339 us; speedup vs baseline: 1.1522x; 1.1099x over previous
//
#include <hip/hip_runtime.h>

typedef __attribute__((ext_vector_type(8))) short short8;
typedef __attribute__((ext_vector_type(4))) short short4v;
typedef __attribute__((ext_vector_type(4))) float float4v;

#define NDIM 512
#define NN (NDIM*NDIM)
#define CD 128

__device__ __forceinline__ unsigned short f2b(float f) {
  union { float f; unsigned u; } v; v.f = f;
  unsigned r = v.u + 0x7FFFu + ((v.u >> 16) & 1u);
  return (unsigned short)(r >> 16);
}
__device__ __forceinline__ float b2f(unsigned short h) {
  union { unsigned u; float f; } v; v.u = ((unsigned)h) << 16; return v.f;
}
__device__ __forceinline__ float sigmoidf_(float x) { return 1.f / (1.f + __expf(-x)); }
// packed f32x2 -> bf16x2 (RNE), single VALU op
__device__ __forceinline__ unsigned pk2(float a, float b) {
  unsigned r;
  asm("v_cvt_pk_bf16_f32 %0, %1, %2" : "=v"(r) : "v"(a), "v"(b));
  return r;
}
__device__ __forceinline__ float4v mfma16(short8 a, short8 b, float4v c) {
  return __builtin_amdgcn_mfma_f32_16x16x32_bf16(a, b, c, 0, 0, 0);
}
__device__ __forceinline__ void gl_lds16(const short* g, short* l) {
  __builtin_amdgcn_global_load_lds(
      (const __attribute__((address_space(1))) unsigned int*)g,
      (__attribute__((address_space(3))) unsigned int*)l, 16, 0, 0);
}

// swizzled LDS tile, rows of 128 shorts (16 chunks of 16B), chunk ^= row&15
__device__ __forceinline__ short8 fragr(const short* buf, int row, int j) {
  return *(const short8*)(buf + row * 128 + ((j ^ (row & 15)) << 3));
}
// 4B write into the same swizzled layout: ku = uint index in [0,64)
__device__ __forceinline__ void stg_w(short* buf, int row, int ku, unsigned v) {
  *(unsigned*)&buf[row * 128 + ((((ku >> 2) ^ (row & 15)) << 3) + ((ku & 3) << 1))] = v;
}

// ---------------- kernel 0: weight prep f32 [k][n] -> bf16 [n][k] ----------------
__global__ __launch_bounds__(256) void kPrepW(
    const float* __restrict__ w0, const float* __restrict__ w1,
    const float* __restrict__ w2, const float* __restrict__ w3,
    const float* __restrict__ w4, short* __restrict__ wt)
{
  const int wi = blockIdx.y;
  const float* W = wi==0 ? w0 : wi==1 ? w1 : wi==2 ? w2 : wi==3 ? w3 : w4;
  const int e = blockIdx.x * 256 + threadIdx.x;   // 0..16383
  const int k = e >> 7, n = e & 127;              // coalesced read along n
  wt[wi * 16384 + n * 128 + k] = (short)f2b(W[k * CD + n]);
}

// ---------------- kernel 1: LN(z) + 5 projections + gating ----------------
// 2048 blocks x 1024 thr; block = 128 rows; wave = 16 rows x 64 channels.
// (r9 known-good: 190 us, absmax 0.03125)
__global__ __launch_bounds__(1024, 4) void kProj(
    const float* __restrict__ z, const float* __restrict__ mask,
    const short* __restrict__ wT,
    const float* __restrict__ b_a_p, const float* __restrict__ b_a_g,
    const float* __restrict__ b_b_p, const float* __restrict__ b_b_g,
    const float* __restrict__ b_g,
    const float* __restrict__ ln_s, const float* __restrict__ ln_b,
    short* __restrict__ a_t, short* __restrict__ b_t, short* __restrict__ g_out)
{
  __shared__ short zln[128 * 128];   // LN result, never overwritten
  __shared__ short sS[128 * 128];    // av/bv [128 ch][128 rows], then gv [128 rows][128 ch]
  __shared__ short wA[128 * 128];    // gate-weight buffer
  __shared__ short wB[128 * 128];    // product-weight buffer
  const int t = threadIdx.x;
  const int r0 = blockIdx.x * 128;
  const int w = t >> 6, l = t & 63, lr = l & 15, lg = l >> 4;
  const int wr = (w >> 1) * 16;      // wave row base within block (0..112)
  const int hc = (w & 1) * 64;       // wave channel-half base

#define STAGE2(BUF, SLOT) do { _Pragma("unroll") for (int i_=0;i_<2;++i_) {  \
    int U_ = i_*1024 + t; int row_ = U_ >> 4, u_ = U_ & 15;                  \
    gl_lds16(wT + (SLOT)*16384 + row_*128 + ((u_^(row_&15))<<3), (BUF)+U_*8); } } while(0)

  STAGE2(wA, 1);                                  // w_a_g
  STAGE2(wB, 0);                                  // w_a_p

  // ---- LN: 8 threads/row, 16 f32 each, 128 rows ----
  {
    const int row = t >> 3, q = t & 7;
    const float* zp = z + (size_t)(r0 + row) * CD + q * 16;
    float x[16];
#pragma unroll
    for (int i = 0; i < 4; ++i) {
      float4v v = *(const float4v*)(zp + i * 4);
#pragma unroll
      for (int e = 0; e < 4; ++e) x[i*4+e] = v[e];
    }
    float s = 0.f;
#pragma unroll
    for (int i = 0; i < 16; ++i) s += x[i];
    s += __shfl_xor(s, 1, 64);
    s += __shfl_xor(s, 2, 64);
    s += __shfl_xor(s, 4, 64);
    const float mu = s * (1.f/128.f);
    float vs = 0.f;
#pragma unroll
    for (int i = 0; i < 16; ++i) { float d = x[i]-mu; vs += d*d; }
    vs += __shfl_xor(vs, 1, 64);
    vs += __shfl_xor(vs, 2, 64);
    vs += __shfl_xor(vs, 4, 64);
    const float rstd = rsqrtf(vs * (1.f/128.f) + 1e-5f);
#pragma unroll
    for (int i = 0; i < 16; i += 2) {
      int c = q*16 + i;
      float y0 = (x[i]  -mu)*rstd*ln_s[c]   + ln_b[c];
      float y1 = (x[i+1]-mu)*rstd*ln_s[c+1] + ln_b[c+1];
      int addr = row*128 + (((c>>3) ^ (row & 15)) << 3) + (c & 7);
      *(unsigned*)(&zln[addr]) = pk2(y0, y1);
    }
  }

  float bga[4], bpa[4], bgb[4], bpb[4];
#pragma unroll
  for (int cf = 0; cf < 4; ++cf) {
    int ci = hc + cf*16 + lr;
    bga[cf] = b_a_g[ci]; bpa[cf] = b_a_p[ci];
    bgb[cf] = b_b_g[ci]; bpb[cf] = b_b_p[ci];
  }
  float mrow[4];
#pragma unroll
  for (int jj = 0; jj < 4; ++jj) mrow[jj] = mask[r0 + wr + lg*4 + jj];

  __syncthreads();                                // B1: zln + wA + wB ready

  short8 af[4];
#pragma unroll
  for (int ks = 0; ks < 4; ++ks)
    af[ks] = fragr(zln, wr + lr, ks*4 + lg);

  float4v accG[4], accB[4];
  float sg[4][4];

#define ZERO4(A) do { _Pragma("unroll") for (int c_=0;c_<4;++c_) A[c_] = (float4v){0.f,0.f,0.f,0.f}; } while(0)

  // 16-MFMA pass: acc[cf] += af[ks] x BUF[hc+cf*16+lr]  (D: row=z-row, col=channel)
#define WP(ACC, BUF) do { ZERO4(ACC);                                      \
  _Pragma("unroll") for (int ks_=0; ks_<4; ++ks_)                          \
    _Pragma("unroll") for (int cf_=0; cf_<4; ++cf_) {                      \
      short8 wf_ = fragr(BUF, hc + cf_*16 + lr, ks_*4 + lg);               \
      ACC[cf_] = mfma16(af[ks_], wf_, ACC[cf_]);                           \
    } } while(0)

#define SIG4(BG) do { _Pragma("unroll") for (int cf_=0;cf_<4;++cf_)        \
    _Pragma("unroll") for (int j_=0;j_<4;++j_)                             \
      sg[cf_][j_] = sigmoidf_(accG[cf_][j_] + BG[cf_]) * mrow[j_]; } while(0)

  // pack sg*(accB+bias) -> sS ch-major: LDS row = channel, uint 2*ku = z-row offset
#define PKAB(BP) do { _Pragma("unroll") for (int cf_=0;cf_<4;++cf_) {      \
    float v0_ = sg[cf_][0]*(accB[cf_][0]+BP[cf_]);                         \
    float v1_ = sg[cf_][1]*(accB[cf_][1]+BP[cf_]);                         \
    float v2_ = sg[cf_][2]*(accB[cf_][2]+BP[cf_]);                         \
    float v3_ = sg[cf_][3]*(accB[cf_][3]+BP[cf_]);                         \
    int ch_ = hc + cf_*16 + lr, ku_ = (wr >> 1) + lg*2;                    \
    stg_w(sS, ch_, ku_,   pk2(v0_, v1_));                                  \
    stg_w(sS, ch_, ku_+1, pk2(v2_, v3_)); } } while(0)

  // full-sector store of sS [128 ch][128 rows] to DST[ch][r0..r0+128): 32B/thread
#define STORE64A(DST) do { int ch_ = t >> 3;                               \
  _Pragma("unroll") for (int i_=0;i_<2;++i_) {                             \
    int cL_ = (t & 7)*2 + i_;                                              \
    *(short8*)(DST + (size_t)ch_*NN + r0 + cL_*8) = fragr(sS, ch_, cL_);   \
  } } while(0)

  // S1: both a-projections
  WP(accG, wA);                                   // a_g
  WP(accB, wB);                                   // a_p
  SIG4(bga);
  PKAB(bpa);                                      // av -> sS
  __syncthreads();                                // B2: weight reads + av writes done

  // S2: restage weights; store a
  STAGE2(wA, 3);                                  // w_b_g
  STAGE2(wB, 2);                                  // w_b_p
  STORE64A(a_t);
  __syncthreads();                                // B3: stages drained; sS reads done

  // S3: both b-projections
  WP(accG, wA);                                   // b_g
  WP(accB, wB);                                   // b_p
  SIG4(bgb);
  PKAB(bpb);                                      // bv -> sS
  __syncthreads();                                // B4

  // S4: stage w_g; store b
  STAGE2(wA, 4);                                  // w_g
  STORE64A(b_t);
  __syncthreads();                                // B5: w_g ready; sS reads done

  // S5: gate projection (swapped: D row=channel, col=z-row), gv -> sS row-major
  {
    float4v accG2[4];
    ZERO4(accG2);
#pragma unroll
    for (int ks = 0; ks < 4; ++ks)
#pragma unroll
      for (int cf = 0; cf < 4; ++cf) {
        short8 wf = fragr(wA, hc + cf*16 + lr, ks*4 + lg);
        accG2[cf] = mfma16(wf, af[ks], accG2[cf]);
      }
#pragma unroll
    for (int cf = 0; cf < 4; ++cf) {
      float4v bgv = *(const float4v*)(b_g + hc + cf*16 + lg*4);
      float v0 = sigmoidf_(accG2[cf][0] + bgv[0]);
      float v1 = sigmoidf_(accG2[cf][1] + bgv[1]);
      float v2 = sigmoidf_(accG2[cf][2] + bgv[2]);
      float v3 = sigmoidf_(accG2[cf][3] + bgv[3]);
      int row = wr + lr, ku = (hc >> 1) + cf*8 + lg*2;
      stg_w(sS, row, ku,   pk2(v0, v1));
      stg_w(sS, row, ku+1, pk2(v2, v3));
    }
  }
  __syncthreads();                                // B6

  // S6: store g (row-major, 256B contiguous per row)
  {
    int row = t >> 3;
#pragma unroll
    for (int i = 0; i < 2; ++i) {
      int cL = (t & 7)*2 + i;
      *(short8*)(g_out + (size_t)(r0 + row)*CD + cL*8) = fragr(sS, row, cL);
    }
  }
}

// ---------------- kernel 2: per-channel einsum GEMM X_c = A_c * B_c^T ----------------
// Counted-vmcnt pipeline (r11, proven-correct).
__global__ __launch_bounds__(256, 2) void kEinsum(const short* __restrict__ a_t,
                                                  const short* __restrict__ b_t,
                                                  short* __restrict__ x_t)
{
  __shared__ short As[2][128 * 64];
  __shared__ short Bs[2][128 * 64];
  const int t = threadIdx.x;
  const int d = blockIdx.x;
  const int c = (d & 7) * 16 + (d >> 7);          // channel -> XCD grouping
  const int tile = (d >> 3) & 15;
  const int i0 = (tile >> 2) * 128;
  const int j0 = (tile & 3) * 128;
  const size_t abase = (size_t)c * NN;
  const int w = t >> 6, l = t & 63, lr = l & 15, lg = l >> 4;
  const int wr = w >> 1, wc = w & 1;

  const short* gA[4]; const short* gB[4]; int ldsU[4];
#pragma unroll
  for (int q = 0; q < 4; ++q) {
    int U = q * 256 + t;
    int row = U >> 3, u = U & 7;
    int swz = ((u ^ (row & 7)) << 3);
    gA[q] = a_t + abase + (size_t)(i0 + row) * NDIM + swz;
    gB[q] = b_t + abase + (size_t)(j0 + row) * NDIM + swz;
    ldsU[q] = U * 8;
  }

#define STAGE_E(buf, k0) do { _Pragma("unroll") for (int q_=0;q_<4;++q_) { \
    gl_lds16(gA[q_] + (k0), &As[buf][ldsU[q_]]);                           \
    gl_lds16(gB[q_] + (k0), &Bs[buf][ldsU[q_]]); } } while(0)

  float4v acc[4][4];
#pragma unroll
  for (int m = 0; m < 4; ++m)
#pragma unroll
    for (int n = 0; n < 4; ++n) acc[m][n] = (float4v){0.f,0.f,0.f,0.f};

  STAGE_E(0, 0);                                  // tile 0 -> buf 0
  STAGE_E(1, 64);                                 // tile 1 -> buf 1 (16 in flight)
#pragma unroll
  for (int it = 0; it < 8; ++it) {
    if (it < 7) asm volatile("s_waitcnt vmcnt(8)" ::: "memory");
    else        asm volatile("s_waitcnt vmcnt(0)" ::: "memory");
    __builtin_amdgcn_sched_barrier(0);
    __builtin_amdgcn_s_barrier();                 // all waves: buf[it&1] complete
    const short* Ab = &As[it & 1][0];
    const short* Bb = &Bs[it & 1][0];
    short8 afr[4][2], bfr[4][2];
#pragma unroll
    for (int m = 0; m < 4; ++m)
#pragma unroll
      for (int ks = 0; ks < 2; ++ks) {
        int row = wr*64 + m*16 + lr, j = ks*4 + lg;
        afr[m][ks] = *(const short8*)(Ab + row*64 + ((j ^ (row & 7)) << 3));
      }
#pragma unroll
    for (int n = 0; n < 4; ++n)
#pragma unroll
      for (int ks = 0; ks < 2; ++ks) {
        int row = wc*64 + n*16 + lr, j = ks*4 + lg;
        bfr[n][ks] = *(const short8*)(Bb + row*64 + ((j ^ (row & 7)) << 3));
      }
    __builtin_amdgcn_s_setprio(1);
#pragma unroll
    for (int ks = 0; ks < 2; ++ks)
#pragma unroll
      for (int m = 0; m < 4; ++m)
#pragma unroll
        for (int n = 0; n < 4; ++n)   // swapped: D = (j, i)
          acc[m][n] = mfma16(bfr[n][ks], afr[m][ks], acc[m][n]);
    __builtin_amdgcn_s_setprio(0);
    __builtin_amdgcn_s_barrier();                 // all waves done reading buf[it&1]
    __builtin_amdgcn_sched_barrier(0);
    if (it < 6) STAGE_E(it & 1, (it + 2) * 64);   // refill freed buffer
  }
  // epilogue: stage x-tile into As region (swizzled), then 128B/thread stores
  short* Xs = &As[0][0];                          // 128 x 128 shorts = 32KB
#pragma unroll
  for (int m = 0; m < 4; ++m)
#pragma unroll
    for (int n = 0; n < 4; ++n) {
      int il = wr*64 + m*16 + lr;
      int ku = wc*32 + n*8 + lg*2;
      stg_w(Xs, il, ku,   pk2(acc[m][n][0], acc[m][n][1]));
      stg_w(Xs, il, ku+1, pk2(acc[m][n][2], acc[m][n][3]));
    }
  __syncthreads();
#pragma unroll
  for (int i = 0; i < 8; ++i) {
    int il = t >> 1, cL = (t & 1)*8 + i;
    *(short8*)(x_t + abase + (size_t)(i0 + il)*NDIM + j0 + cL*8) = fragr(Xs, il, cL);
  }
}

// ---------------- kernel 3: LN(x) + x@w_z + b_z, * gate (v2) ----------------
// 2048 blocks x 1024 thr; block = 128 rows; wave = 16 rows x 64 channels.
// 3 barriers; gate early-loaded to regs, staged to LDS; direct 64B-sector stores.
__global__ __launch_bounds__(1024, 4) void kOut(
    const short* __restrict__ x_t, const short* __restrict__ g_in,
    const float* __restrict__ w_z, const float* __restrict__ b_z,
    const float* __restrict__ ln_s, const float* __restrict__ ln_b,
    float* __restrict__ out)
{
  __shared__ short xs[128 * 128];   // gathered x [ch][rows], swizzle key (ch>>3)&15; sG after s2
  __shared__ short xln[128 * 128];  // LN result, swizzle key row&15
  __shared__ short sW[128 * 128];   // w_z bf16 [n][k], swizzle key row&15
  const int t = threadIdx.x;
  const int r0 = blockIdx.x * 128;
  const int w = t >> 6, l = t & 63, lr = l & 15, lg = l >> 4;
  const int rowb = (w >> 1) * 16;   // wave row base
  const int hc = (w & 1) * 64;      // wave channel-half base

  // A) early gate loads -> regs (coalesced 16B/lane; T14 issue-early)
  short8 gv[2];
#pragma unroll
  for (int v = 0; v < 2; ++v) {
    int V = v*1024 + t; int row = V >> 4, u = V & 15;
    gv[v] = *(const short8*)(g_in + (size_t)(r0 + row) * CD + u * 8);
  }
  // B) gather x columns -> xs via gl_lds (pre-swizzled source, key (cc>>3)&15)
#pragma unroll
  for (int v = 0; v < 2; ++v) {
    int U = v*1024 + t; int cc = U >> 4, u = U & 15;
    gl_lds16(x_t + (size_t)cc * NN + r0 + ((u ^ ((cc >> 3) & 15)) << 3), xs + U*8);
  }
  // C) stage w_z f32 [k][n] -> swizzled bf16 [n][k]
#pragma unroll
  for (int i = 0; i < 2; ++i) {
    int flat = i*1024 + t;
    int kp = flat >> 5, k = kp * 2, n4 = (flat & 31) * 4;
    float4v va = *(const float4v*)(w_z + (size_t)k * CD + n4);
    float4v vb = *(const float4v*)(w_z + (size_t)(k + 1) * CD + n4);
#pragma unroll
    for (int j = 0; j < 4; ++j) {
      int row = n4 + j;
      int addr = row * 128 + (((k >> 3) ^ (row & 15)) << 3) + (k & 7);
      *(unsigned*)(&sW[addr]) = pk2(va[j], vb[j]);
    }
  }
  __syncthreads();                                // s1: xs + sW ready
  // D) LN over channels: 8 thr/row, 16 ch each
  {
    const int r = t >> 3, q = t & 7;
    float x[16];
#pragma unroll
    for (int i = 0; i < 16; ++i) {
      int c = q*16 + i;
      x[i] = b2f((unsigned short)xs[c*128 + (((r >> 3) ^ ((c >> 3) & 15)) << 3) + (r & 7)]);
    }
    float s = 0.f;
#pragma unroll
    for (int i = 0; i < 16; ++i) s += x[i];
    s += __shfl_xor(s, 1, 64);
    s += __shfl_xor(s, 2, 64);
    s += __shfl_xor(s, 4, 64);
    const float mu = s * (1.f/128.f);
    float vs = 0.f;
#pragma unroll
    for (int i = 0; i < 16; ++i) { float d = x[i]-mu; vs += d*d; }
    vs += __shfl_xor(vs, 1, 64);
    vs += __shfl_xor(vs, 2, 64);
    vs += __shfl_xor(vs, 4, 64);
    const float rstd = rsqrtf(vs * (1.f/128.f) + 1e-5f);
#pragma unroll
    for (int i = 0; i < 16; i += 2) {
      int c = q*16 + i;
      float y0 = (x[i]  -mu)*rstd*ln_s[c]   + ln_b[c];
      float y1 = (x[i+1]-mu)*rstd*ln_s[c+1] + ln_b[c+1];
      int addr = r*128 + (((c>>3) ^ (r & 15)) << 3) + (c & 7);
      *(unsigned*)(&xln[addr]) = pk2(y0, y1);
    }
  }
  __syncthreads();                                // s2: xln ready; xs dead
  // E) gate -> sG (xs region); fragments; MFMA (unswapped: D row=z-row, col=ch)
  short* sG = xs;
#pragma unroll
  for (int v = 0; v < 2; ++v) {
    int V = v*1024 + t; int row = V >> 4, u = V & 15;
    *(short8*)(sG + row*128 + ((u ^ (row & 15)) << 3)) = gv[v];
  }
  short8 af[4];
#pragma unroll
  for (int ks = 0; ks < 4; ++ks)
    af[ks] = fragr(xln, rowb + lr, ks*4 + lg);
  float4v acc[4];
#pragma unroll
  for (int cf = 0; cf < 4; ++cf) acc[cf] = (float4v){0.f,0.f,0.f,0.f};
#pragma unroll
  for (int ks = 0; ks < 4; ++ks)
#pragma unroll
    for (int cf = 0; cf < 4; ++cf) {
      short8 wf = fragr(sW, hc + cf*16 + lr, ks*4 + lg);
      acc[cf] = mfma16(af[ks], wf, acc[cf]);
    }
  float bz[4];
#pragma unroll
  for (int cf = 0; cf < 4; ++cf) bz[cf] = b_z[hc + cf*16 + lr];
  __syncthreads();                                // s3: sG ready
  // F) gated output, direct full-sector stores (16 lanes x 4B = 64B per (cf,jj))
#pragma unroll
  for (int cf = 0; cf < 4; ++cf) {
    int ch = hc + cf*16 + lr;
#pragma unroll
    for (int jj = 0; jj < 4; ++jj) {
      int row = rowb + lg*4 + jj;
      float gvv = b2f((unsigned short)sG[row*128 + (((ch>>3) ^ (row & 15)) << 3) + (ch & 7)]);
      out[(size_t)(r0 + row) * CD + ch] = (acc[cf][jj] + bz[cf]) * gvv;
    }
  }
}

extern "C" void kernel_launch(void* const* d_in, const int* in_sizes, int n_in,
                              void* d_out, int out_size, void* d_ws, size_t ws_size,
                              hipStream_t stream) {
  (void)in_sizes; (void)n_in; (void)out_size; (void)ws_size;
  const float* z     = (const float*)d_in[0];
  const float* mask  = (const float*)d_in[1];
  const float* w_a_p = (const float*)d_in[2];
  const float* b_a_p = (const float*)d_in[3];
  const float* w_a_g = (const float*)d_in[4];
  const float* b_a_g = (const float*)d_in[5];
  const float* w_b_p = (const float*)d_in[6];
  const float* b_b_p = (const float*)d_in[7];
  const float* w_b_g = (const float*)d_in[8];
  const float* b_b_g = (const float*)d_in[9];
  const float* w_g   = (const float*)d_in[10];
  const float* b_g   = (const float*)d_in[11];
  const float* w_z   = (const float*)d_in[12];
  const float* b_z   = (const float*)d_in[13];
  const float* ln_i_s = (const float*)d_in[14];
  const float* ln_i_b = (const float*)d_in[15];
  const float* ln_o_s = (const float*)d_in[16];
  const float* ln_o_b = (const float*)d_in[17];

  short* a_t = (short*)d_ws;
  short* b_t = a_t + (size_t)CD*NN;
  short* g_s = b_t + (size_t)CD*NN;
  short* x_t = g_s + (size_t)CD*NN;
  short* wT  = x_t;                                // 160 KB at head of x_t (kProj only)

  hipLaunchKernelGGL(kPrepW, dim3(64, 5), dim3(256), 0, stream,
                     w_a_p, w_a_g, w_b_p, w_b_g, w_g, wT);
  hipLaunchKernelGGL(kProj, dim3(NN/128), dim3(1024), 0, stream,
                     z, mask, wT, b_a_p, b_a_g, b_b_p, b_b_g, b_g,
                     ln_i_s, ln_i_b, a_t, b_t, g_s);
  hipLaunchKernelGGL(kEinsum, dim3(2048), dim3(256), 0, stream, a_t, b_t, x_t);
  hipLaunchKernelGGL(kOut, dim3(NN/128), dim3(1024), 0, stream,
                     x_t, g_s, w_z, b_z, ln_o_s, ln_o_b, (float*)d_out);
}

// Round 13
// 311.743 us; speedup vs baseline: 1.1544x; 1.0019x over previous
//
#include <hip/hip_runtime.h>

typedef __attribute__((ext_vector_type(8))) short short8;
typedef __attribute__((ext_vector_type(4))) short short4v;
typedef __attribute__((ext_vector_type(4))) float float4v;

#define NDIM 512
#define NN (NDIM*NDIM)
#define CD 128

__device__ __forceinline__ unsigned short f2b(float f) {
  union { float f; unsigned u; } v; v.f = f;
  unsigned r = v.u + 0x7FFFu + ((v.u >> 16) & 1u);
  return (unsigned short)(r >> 16);
}
__device__ __forceinline__ float b2f(unsigned short h) {
  union { unsigned u; float f; } v; v.u = ((unsigned)h) << 16; return v.f;
}
__device__ __forceinline__ float sigmoidf_(float x) {
  return __fdividef(1.f, 1.f + __expf(-x));     // rcp+mul, not IEEE div sequence
}
// packed f32x2 -> bf16x2 (RNE), single VALU op
__device__ __forceinline__ unsigned pk2(float a, float b) {
  unsigned r;
  asm("v_cvt_pk_bf16_f32 %0, %1, %2" : "=v"(r) : "v"(a), "v"(b));
  return r;
}
__device__ __forceinline__ float4v mfma16(short8 a, short8 b, float4v c) {
  return __builtin_amdgcn_mfma_f32_16x16x32_bf16(a, b, c, 0, 0, 0);
}
__device__ __forceinline__ void gl_lds16(const short* g, short* l) {
  __builtin_amdgcn_global_load_lds(
      (const __attribute__((address_space(1))) unsigned int*)g,
      (__attribute__((address_space(3))) unsigned int*)l, 16, 0, 0);
}

// swizzled LDS tile, rows of 128 shorts (16 chunks of 16B), chunk ^= row&15
__device__ __forceinline__ short8 fragr(const short* buf, int row, int j) {
  return *(const short8*)(buf + row * 128 + ((j ^ (row & 15)) << 3));
}
// 4B write into the same swizzled layout: ku = uint index in [0,64)
__device__ __forceinline__ void stg_w(short* buf, int row, int ku, unsigned v) {
  *(unsigned*)&buf[row * 128 + ((((ku >> 2) ^ (row & 15)) << 3) + ((ku & 3) << 1))] = v;
}
// paired 8B write: requires ku even and (ku&3)<=2 (both 4B slots in one 16B chunk)
__device__ __forceinline__ void stg_w2(short* buf, int row, int ku, unsigned v0, unsigned v1) {
  unsigned long long v = (unsigned long long)v0 | ((unsigned long long)v1 << 32);
  *(unsigned long long*)&buf[row * 128 + ((((ku >> 2) ^ (row & 15)) << 3) + ((ku & 3) << 1))] = v;
}

// ---------------- kernel 0: weight prep f32 [k][n] -> bf16 [n][k] ----------------
__global__ __launch_bounds__(256) void kPrepW(
    const float* __restrict__ w0, const float* __restrict__ w1,
    const float* __restrict__ w2, const float* __restrict__ w3,
    const float* __restrict__ w4, short* __restrict__ wt)
{
  const int wi = blockIdx.y;
  const float* W = wi==0 ? w0 : wi==1 ? w1 : wi==2 ? w2 : wi==3 ? w3 : w4;
  const int e = blockIdx.x * 256 + threadIdx.x;   // 0..16383
  const int k = e >> 7, n = e & 127;              // coalesced read along n
  wt[wi * 16384 + n * 128 + k] = (short)f2b(W[k * CD + n]);
}

// ---------------- kernel 1: LN(z) + 5 projections + gating ----------------
// 2048 blocks x 1024 thr; block = 128 rows; wave = 16 rows x 64 channels.
__global__ __launch_bounds__(1024, 4) void kProj(
    const float* __restrict__ z, const float* __restrict__ mask,
    const short* __restrict__ wT,
    const float* __restrict__ b_a_p, const float* __restrict__ b_a_g,
    const float* __restrict__ b_b_p, const float* __restrict__ b_b_g,
    const float* __restrict__ b_g,
    const float* __restrict__ ln_s, const float* __restrict__ ln_b,
    short* __restrict__ a_t, short* __restrict__ b_t, short* __restrict__ g_out)
{
  __shared__ short zln[128 * 128];   // LN result, never overwritten
  __shared__ short sS[128 * 128];    // av/bv [128 ch][128 rows], then gv [128 rows][128 ch]
  __shared__ short wA[128 * 128];    // gate-weight buffer
  __shared__ short wB[128 * 128];    // product-weight buffer
  const int t = threadIdx.x;
  const int r0 = blockIdx.x * 128;
  const int w = t >> 6, l = t & 63, lr = l & 15, lg = l >> 4;
  const int wr = (w >> 1) * 16;      // wave row base within block (0..112)
  const int hc = (w & 1) * 64;       // wave channel-half base

#define STAGE2(BUF, SLOT) do { _Pragma("unroll") for (int i_=0;i_<2;++i_) {  \
    int U_ = i_*1024 + t; int row_ = U_ >> 4, u_ = U_ & 15;                  \
    gl_lds16(wT + (SLOT)*16384 + row_*128 + ((u_^(row_&15))<<3), (BUF)+U_*8); } } while(0)

  STAGE2(wA, 1);                                  // w_a_g
  STAGE2(wB, 0);                                  // w_a_p

  // ---- LN: 8 threads/row, 16 f32 each, 128 rows ----
  {
    const int row = t >> 3, q = t & 7;
    const float* zp = z + (size_t)(r0 + row) * CD + q * 16;
    float x[16];
#pragma unroll
    for (int i = 0; i < 4; ++i) {
      float4v v = *(const float4v*)(zp + i * 4);
#pragma unroll
      for (int e = 0; e < 4; ++e) x[i*4+e] = v[e];
    }
    float s = 0.f;
#pragma unroll
    for (int i = 0; i < 16; ++i) s += x[i];
    s += __shfl_xor(s, 1, 64);
    s += __shfl_xor(s, 2, 64);
    s += __shfl_xor(s, 4, 64);
    const float mu = s * (1.f/128.f);
    float vs = 0.f;
#pragma unroll
    for (int i = 0; i < 16; ++i) { float d = x[i]-mu; vs += d*d; }
    vs += __shfl_xor(vs, 1, 64);
    vs += __shfl_xor(vs, 2, 64);
    vs += __shfl_xor(vs, 4, 64);
    const float rstd = rsqrtf(vs * (1.f/128.f) + 1e-5f);
#pragma unroll
    for (int i = 0; i < 16; i += 4) {             // paired 8B LDS stores
      int c = q*16 + i;
      float y0 = (x[i]  -mu)*rstd*ln_s[c]   + ln_b[c];
      float y1 = (x[i+1]-mu)*rstd*ln_s[c+1] + ln_b[c+1];
      float y2 = (x[i+2]-mu)*rstd*ln_s[c+2] + ln_b[c+2];
      float y3 = (x[i+3]-mu)*rstd*ln_s[c+3] + ln_b[c+3];
      int addr = row*128 + (((c>>3) ^ (row & 15)) << 3) + (c & 7);
      unsigned long long pv = (unsigned long long)pk2(y0, y1)
                            | ((unsigned long long)pk2(y2, y3) << 32);
      *(unsigned long long*)(&zln[addr]) = pv;
    }
  }

  float bga[4], bpa[4], bgb[4], bpb[4];
#pragma unroll
  for (int cf = 0; cf < 4; ++cf) {
    int ci = hc + cf*16 + lr;
    bga[cf] = b_a_g[ci]; bpa[cf] = b_a_p[ci];
    bgb[cf] = b_b_g[ci]; bpb[cf] = b_b_p[ci];
  }
  float mrow[4];
#pragma unroll
  for (int jj = 0; jj < 4; ++jj) mrow[jj] = mask[r0 + wr + lg*4 + jj];

  __syncthreads();                                // B1: zln + wA + wB ready

  short8 af[4];
#pragma unroll
  for (int ks = 0; ks < 4; ++ks)
    af[ks] = fragr(zln, wr + lr, ks*4 + lg);

  float4v accG[4], accB[4];
  float sg[4][4];

#define ZERO4(A) do { _Pragma("unroll") for (int c_=0;c_<4;++c_) A[c_] = (float4v){0.f,0.f,0.f,0.f}; } while(0)

  // 16-MFMA pass: acc[cf] += af[ks] x BUF[hc+cf*16+lr]  (D: row=z-row, col=channel)
#define WP(ACC, BUF) do { ZERO4(ACC);                                      \
  _Pragma("unroll") for (int ks_=0; ks_<4; ++ks_)                          \
    _Pragma("unroll") for (int cf_=0; cf_<4; ++cf_) {                      \
      short8 wf_ = fragr(BUF, hc + cf_*16 + lr, ks_*4 + lg);               \
      ACC[cf_] = mfma16(af[ks_], wf_, ACC[cf_]);                           \
    } } while(0)

#define SIG4(BG) do { _Pragma("unroll") for (int cf_=0;cf_<4;++cf_)        \
    _Pragma("unroll") for (int j_=0;j_<4;++j_)                             \
      sg[cf_][j_] = sigmoidf_(accG[cf_][j_] + BG[cf_]) * mrow[j_]; } while(0)

  // pack sg*(accB+bias) -> sS ch-major (one 8B write per cf)
#define PKAB(BP) do { _Pragma("unroll") for (int cf_=0;cf_<4;++cf_) {      \
    float v0_ = sg[cf_][0]*(accB[cf_][0]+BP[cf_]);                         \
    float v1_ = sg[cf_][1]*(accB[cf_][1]+BP[cf_]);                         \
    float v2_ = sg[cf_][2]*(accB[cf_][2]+BP[cf_]);                         \
    float v3_ = sg[cf_][3]*(accB[cf_][3]+BP[cf_]);                         \
    int ch_ = hc + cf_*16 + lr, ku_ = (wr >> 1) + lg*2;                    \
    stg_w2(sS, ch_, ku_, pk2(v0_, v1_), pk2(v2_, v3_)); } } while(0)

  // full-sector store of sS [128 ch][128 rows] to DST[ch][r0..r0+128): 32B/thread
#define STORE64A(DST) do { int ch_ = t >> 3;                               \
  _Pragma("unroll") for (int i_=0;i_<2;++i_) {                             \
    int cL_ = (t & 7)*2 + i_;                                              \
    *(short8*)(DST + (size_t)ch_*NN + r0 + cL_*8) = fragr(sS, ch_, cL_);   \
  } } while(0)

  // S1: both a-projections
  WP(accG, wA);                                   // a_g
  WP(accB, wB);                                   // a_p
  SIG4(bga);
  PKAB(bpa);                                      // av -> sS
  __syncthreads();                                // B2: weight reads + av writes done

  // S2: restage weights; store a
  STAGE2(wA, 3);                                  // w_b_g
  STAGE2(wB, 2);                                  // w_b_p
  STORE64A(a_t);
  __syncthreads();                                // B3: stages drained; sS reads done

  // S3: both b-projections
  WP(accG, wA);                                   // b_g
  WP(accB, wB);                                   // b_p
  SIG4(bgb);
  PKAB(bpb);                                      // bv -> sS
  __syncthreads();                                // B4

  // S4: stage w_g; store b
  STAGE2(wA, 4);                                  // w_g
  STORE64A(b_t);
  __syncthreads();                                // B5: w_g ready; sS reads done

  // S5: gate projection (swapped: D row=channel, col=z-row), gv -> sS row-major
  {
    float4v accG2[4];
    ZERO4(accG2);
#pragma unroll
    for (int ks = 0; ks < 4; ++ks)
#pragma unroll
      for (int cf = 0; cf < 4; ++cf) {
        short8 wf = fragr(wA, hc + cf*16 + lr, ks*4 + lg);
        accG2[cf] = mfma16(wf, af[ks], accG2[cf]);
      }
#pragma unroll
    for (int cf = 0; cf < 4; ++cf) {
      float4v bgv = *(const float4v*)(b_g + hc + cf*16 + lg*4);
      float v0 = sigmoidf_(accG2[cf][0] + bgv[0]);
      float v1 = sigmoidf_(accG2[cf][1] + bgv[1]);
      float v2 = sigmoidf_(accG2[cf][2] + bgv[2]);
      float v3 = sigmoidf_(accG2[cf][3] + bgv[3]);
      int row = wr + lr, ku = (hc >> 1) + cf*8 + lg*2;
      stg_w2(sS, row, ku, pk2(v0, v1), pk2(v2, v3));
    }
  }
  __syncthreads();                                // B6

  // S6: store g (row-major, 256B contiguous per row)
  {
    int row = t >> 3;
#pragma unroll
    for (int i = 0; i < 2; ++i) {
      int cL = (t & 7)*2 + i;
      *(short8*)(g_out + (size_t)(r0 + row)*CD + cL*8) = fragr(sS, row, cL);
    }
  }
}

// ---------------- kernel 2: per-channel einsum GEMM X_c = A_c * B_c^T ----------------
// Counted-vmcnt pipeline (r11, proven-correct).
__global__ __launch_bounds__(256, 2) void kEinsum(const short* __restrict__ a_t,
                                                  const short* __restrict__ b_t,
                                                  short* __restrict__ x_t)
{
  __shared__ short As[2][128 * 64];
  __shared__ short Bs[2][128 * 64];
  const int t = threadIdx.x;
  const int d = blockIdx.x;
  const int c = (d & 7) * 16 + (d >> 7);          // channel -> XCD grouping
  const int tile = (d >> 3) & 15;
  const int i0 = (tile >> 2) * 128;
  const int j0 = (tile & 3) * 128;
  const size_t abase = (size_t)c * NN;
  const int w = t >> 6, l = t & 63, lr = l & 15, lg = l >> 4;
  const int wr = w >> 1, wc = w & 1;

  const short* gA[4]; const short* gB[4]; int ldsU[4];
#pragma unroll
  for (int q = 0; q < 4; ++q) {
    int U = q * 256 + t;
    int row = U >> 3, u = U & 7;
    int swz = ((u ^ (row & 7)) << 3);
    gA[q] = a_t + abase + (size_t)(i0 + row) * NDIM + swz;
    gB[q] = b_t + abase + (size_t)(j0 + row) * NDIM + swz;
    ldsU[q] = U * 8;
  }

#define STAGE_E(buf, k0) do { _Pragma("unroll") for (int q_=0;q_<4;++q_) { \
    gl_lds16(gA[q_] + (k0), &As[buf][ldsU[q_]]);                           \
    gl_lds16(gB[q_] + (k0), &Bs[buf][ldsU[q_]]); } } while(0)

  float4v acc[4][4];
#pragma unroll
  for (int m = 0; m < 4; ++m)
#pragma unroll
    for (int n = 0; n < 4; ++n) acc[m][n] = (float4v){0.f,0.f,0.f,0.f};

  STAGE_E(0, 0);                                  // tile 0 -> buf 0
  STAGE_E(1, 64);                                 // tile 1 -> buf 1 (16 in flight)
#pragma unroll
  for (int it = 0; it < 8; ++it) {
    if (it < 7) asm volatile("s_waitcnt vmcnt(8)" ::: "memory");
    else        asm volatile("s_waitcnt vmcnt(0)" ::: "memory");
    __builtin_amdgcn_sched_barrier(0);
    __builtin_amdgcn_s_barrier();                 // all waves: buf[it&1] complete
    const short* Ab = &As[it & 1][0];
    const short* Bb = &Bs[it & 1][0];
    short8 afr[4][2], bfr[4][2];
#pragma unroll
    for (int m = 0; m < 4; ++m)
#pragma unroll
      for (int ks = 0; ks < 2; ++ks) {
        int row = wr*64 + m*16 + lr, j = ks*4 + lg;
        afr[m][ks] = *(const short8*)(Ab + row*64 + ((j ^ (row & 7)) << 3));
      }
#pragma unroll
    for (int n = 0; n < 4; ++n)
#pragma unroll
      for (int ks = 0; ks < 2; ++ks) {
        int row = wc*64 + n*16 + lr, j = ks*4 + lg;
        bfr[n][ks] = *(const short8*)(Bb + row*64 + ((j ^ (row & 7)) << 3));
      }
    __builtin_amdgcn_s_setprio(1);
#pragma unroll
    for (int ks = 0; ks < 2; ++ks)
#pragma unroll
      for (int m = 0; m < 4; ++m)
#pragma unroll
        for (int n = 0; n < 4; ++n)   // swapped: D = (j, i)
          acc[m][n] = mfma16(bfr[n][ks], afr[m][ks], acc[m][n]);
    __builtin_amdgcn_s_setprio(0);
    __builtin_amdgcn_s_barrier();                 // all waves done reading buf[it&1]
    __builtin_amdgcn_sched_barrier(0);
    if (it < 6) STAGE_E(it & 1, (it + 2) * 64);   // refill freed buffer
  }
  // epilogue: stage x-tile into As region (swizzled), then 128B/thread stores
  short* Xs = &As[0][0];                          // 128 x 128 shorts = 32KB
#pragma unroll
  for (int m = 0; m < 4; ++m)
#pragma unroll
    for (int n = 0; n < 4; ++n) {
      int il = wr*64 + m*16 + lr;
      int ku = wc*32 + n*8 + lg*2;
      stg_w2(Xs, il, ku, pk2(acc[m][n][0], acc[m][n][1]),
                         pk2(acc[m][n][2], acc[m][n][3]));
    }
  __syncthreads();
#pragma unroll
  for (int i = 0; i < 8; ++i) {
    int il = t >> 1, cL = (t & 1)*8 + i;
    *(short8*)(x_t + abase + (size_t)(i0 + il)*NDIM + j0 + cL*8) = fragr(Xs, il, cL);
  }
}

// ---------------- kernel 3: LN(x) + x@w_z + b_z, * gate (v2) ----------------
// 2048 blocks x 1024 thr; block = 128 rows; wave = 16 rows x 64 channels.
__global__ __launch_bounds__(1024, 4) void kOut(
    const short* __restrict__ x_t, const short* __restrict__ g_in,
    const float* __restrict__ w_z, const float* __restrict__ b_z,
    const float* __restrict__ ln_s, const float* __restrict__ ln_b,
    float* __restrict__ out)
{
  __shared__ short xs[128 * 128];   // gathered x [ch][rows], swizzle key (ch>>3)&15; sG after s2
  __shared__ short xln[128 * 128];  // LN result, swizzle key row&15
  __shared__ short sW[128 * 128];   // w_z bf16 [n][k], swizzle key row&15
  const int t = threadIdx.x;
  const int r0 = blockIdx.x * 128;
  const int w = t >> 6, l = t & 63, lr = l & 15, lg = l >> 4;
  const int rowb = (w >> 1) * 16;   // wave row base
  const int hc = (w & 1) * 64;      // wave channel-half base

  // A) early gate loads -> regs (coalesced 16B/lane)
  short8 gv[2];
#pragma unroll
  for (int v = 0; v < 2; ++v) {
    int V = v*1024 + t; int row = V >> 4, u = V & 15;
    gv[v] = *(const short8*)(g_in + (size_t)(r0 + row) * CD + u * 8);
  }
  // B) gather x columns -> xs via gl_lds (pre-swizzled source, key (cc>>3)&15)
#pragma unroll
  for (int v = 0; v < 2; ++v) {
    int U = v*1024 + t; int cc = U >> 4, u = U & 15;
    gl_lds16(x_t + (size_t)cc * NN + r0 + ((u ^ ((cc >> 3) & 15)) << 3), xs + U*8);
  }
  // C) stage w_z f32 [k][n] -> swizzled bf16 [n][k]
#pragma unroll
  for (int i = 0; i < 2; ++i) {
    int flat = i*1024 + t;
    int kp = flat >> 5, k = kp * 2, n4 = (flat & 31) * 4;
    float4v va = *(const float4v*)(w_z + (size_t)k * CD + n4);
    float4v vb = *(const float4v*)(w_z + (size_t)(k + 1) * CD + n4);
#pragma unroll
    for (int j = 0; j < 4; ++j) {
      int row = n4 + j;
      int addr = row * 128 + (((k >> 3) ^ (row & 15)) << 3) + (k & 7);
      *(unsigned*)(&sW[addr]) = pk2(va[j], vb[j]);
    }
  }
  __syncthreads();                                // s1: xs + sW ready
  // D) LN over channels: 8 thr/row, 16 ch each
  {
    const int r = t >> 3, q = t & 7;
    float x[16];
#pragma unroll
    for (int i = 0; i < 16; ++i) {
      int c = q*16 + i;
      x[i] = b2f((unsigned short)xs[c*128 + (((r >> 3) ^ ((c >> 3) & 15)) << 3) + (r & 7)]);
    }
    float s = 0.f;
#pragma unroll
    for (int i = 0; i < 16; ++i) s += x[i];
    s += __shfl_xor(s, 1, 64);
    s += __shfl_xor(s, 2, 64);
    s += __shfl_xor(s, 4, 64);
    const float mu = s * (1.f/128.f);
    float vs = 0.f;
#pragma unroll
    for (int i = 0; i < 16; ++i) { float d = x[i]-mu; vs += d*d; }
    vs += __shfl_xor(vs, 1, 64);
    vs += __shfl_xor(vs, 2, 64);
    vs += __shfl_xor(vs, 4, 64);
    const float rstd = rsqrtf(vs * (1.f/128.f) + 1e-5f);
#pragma unroll
    for (int i = 0; i < 16; i += 4) {             // paired 8B LDS stores
      int c = q*16 + i;
      float y0 = (x[i]  -mu)*rstd*ln_s[c]   + ln_b[c];
      float y1 = (x[i+1]-mu)*rstd*ln_s[c+1] + ln_b[c+1];
      float y2 = (x[i+2]-mu)*rstd*ln_s[c+2] + ln_b[c+2];
      float y3 = (x[i+3]-mu)*rstd*ln_s[c+3] + ln_b[c+3];
      int addr = r*128 + (((c>>3) ^ (r & 15)) << 3) + (c & 7);
      unsigned long long pv = (unsigned long long)pk2(y0, y1)
                            | ((unsigned long long)pk2(y2, y3) << 32);
      *(unsigned long long*)(&xln[addr]) = pv;
    }
  }
  __syncthreads();                                // s2: xln ready; xs dead
  // E) gate -> sG (xs region); fragments; MFMA (unswapped: D row=z-row, col=ch)
  short* sG = xs;
#pragma unroll
  for (int v = 0; v < 2; ++v) {
    int V = v*1024 + t; int row = V >> 4, u = V & 15;
    *(short8*)(sG + row*128 + ((u ^ (row & 15)) << 3)) = gv[v];
  }
  short8 af[4];
#pragma unroll
  for (int ks = 0; ks < 4; ++ks)
    af[ks] = fragr(xln, rowb + lr, ks*4 + lg);
  float4v acc[4];
#pragma unroll
  for (int cf = 0; cf < 4; ++cf) acc[cf] = (float4v){0.f,0.f,0.f,0.f};
#pragma unroll
  for (int ks = 0; ks < 4; ++ks)
#pragma unroll
    for (int cf = 0; cf < 4; ++cf) {
      short8 wf = fragr(sW, hc + cf*16 + lr, ks*4 + lg);
      acc[cf] = mfma16(af[ks], wf, acc[cf]);
    }
  float bz[4];
#pragma unroll
  for (int cf = 0; cf < 4; ++cf) bz[cf] = b_z[hc + cf*16 + lr];
  __syncthreads();                                // s3: sG ready
  // F) gated output, direct full-sector stores (16 lanes x 4B = 64B per (cf,jj))
#pragma unroll
  for (int cf = 0; cf < 4; ++cf) {
    int ch = hc + cf*16 + lr;
#pragma unroll
    for (int jj = 0; jj < 4; ++jj) {
      int row = rowb + lg*4 + jj;
      float gvv = b2f((unsigned short)sG[row*128 + (((ch>>3) ^ (row & 15)) << 3) + (ch & 7)]);
      out[(size_t)(r0 + row) * CD + ch] = (acc[cf][jj] + bz[cf]) * gvv;
    }
  }
}

extern "C" void kernel_launch(void* const* d_in, const int* in_sizes, int n_in,
                              void* d_out, int out_size, void* d_ws, size_t ws_size,
                              hipStream_t stream) {
  (void)in_sizes; (void)n_in; (void)out_size; (void)ws_size;
  const float* z     = (const float*)d_in[0];
  const float* mask  = (const float*)d_in[1];
  const float* w_a_p = (const float*)d_in[2];
  const float* b_a_p = (const float*)d_in[3];
  const float* w_a_g = (const float*)d_in[4];
  const float* b_a_g = (const float*)d_in[5];
  const float* w_b_p = (const float*)d_in[6];
  const float* b_b_p = (const float*)d_in[7];
  const float* w_b_g = (const float*)d_in[8];
  const float* b_b_g = (const float*)d_in[9];
  const float* w_g   = (const float*)d_in[10];
  const float* b_g   = (const float*)d_in[11];
  const float* w_z   = (const float*)d_in[12];
  const float* b_z   = (const float*)d_in[13];
  const float* ln_i_s = (const float*)d_in[14];
  const float* ln_i_b = (const float*)d_in[15];
  const float* ln_o_s = (const float*)d_in[16];
  const float* ln_o_b = (const float*)d_in[17];

  short* a_t = (short*)d_ws;
  short* b_t = a_t + (size_t)CD*NN;
  short* g_s = b_t + (size_t)CD*NN;
  short* x_t = g_s + (size_t)CD*NN;
  short* wT  = x_t;                                // 160 KB at head of x_t (kProj only)

  hipLaunchKernelGGL(kPrepW, dim3(64, 5), dim3(256), 0, stream,
                     w_a_p, w_a_g, w_b_p, w_b_g, w_g, wT);
  hipLaunchKernelGGL(kProj, dim3(NN/128), dim3(1024), 0, stream,
                     z, mask, wT, b_a_p, b_a_g, b_b_p, b_b_g, b_g,
                     ln_i_s, ln_i_b, a_t, b_t, g_s);
  hipLaunchKernelGGL(kEinsum, dim3(2048), dim3(256), 0, stream, a_t, b_t, x_t);
  hipLaunchKernelGGL(kOut, dim3(NN/128), dim3(1024), 0, stream,
                     x_t, g_s, w_z, b_z, ln_o_s, ln_o_b, (float*)d_out);
}

// Round 14
// 308.916 us; speedup vs baseline: 1.1650x; 1.0092x over previous
//
#include <hip/hip_runtime.h>

typedef __attribute__((ext_vector_type(8))) short short8;
typedef __attribute__((ext_vector_type(4))) short short4v;
typedef __attribute__((ext_vector_type(4))) float float4v;

#define NDIM 512
#define NN (NDIM*NDIM)
#define CD 128

__device__ __forceinline__ unsigned short f2b(float f) {
  union { float f; unsigned u; } v; v.f = f;
  unsigned r = v.u + 0x7FFFu + ((v.u >> 16) & 1u);
  return (unsigned short)(r >> 16);
}
__device__ __forceinline__ float b2f(unsigned short h) {
  union { unsigned u; float f; } v; v.u = ((unsigned)h) << 16; return v.f;
}
__device__ __forceinline__ float sigmoidf_(float x) {
  return __fdividef(1.f, 1.f + __expf(-x));     // rcp+mul, not IEEE div sequence
}
// packed f32x2 -> bf16x2 (RNE), single VALU op
__device__ __forceinline__ unsigned pk2(float a, float b) {
  unsigned r;
  asm("v_cvt_pk_bf16_f32 %0, %1, %2" : "=v"(r) : "v"(a), "v"(b));
  return r;
}
__device__ __forceinline__ float4v mfma16(short8 a, short8 b, float4v c) {
  return __builtin_amdgcn_mfma_f32_16x16x32_bf16(a, b, c, 0, 0, 0);
}
__device__ __forceinline__ void gl_lds16(const short* g, short* l) {
  __builtin_amdgcn_global_load_lds(
      (const __attribute__((address_space(1))) unsigned int*)g,
      (__attribute__((address_space(3))) unsigned int*)l, 16, 0, 0);
}

// swizzled LDS tile, rows of 128 shorts (16 chunks of 16B), chunk ^= row&15
__device__ __forceinline__ short8 fragr(const short* buf, int row, int j) {
  return *(const short8*)(buf + row * 128 + ((j ^ (row & 15)) << 3));
}
// 4B write into the same swizzled layout: ku = uint index in [0,64)
__device__ __forceinline__ void stg_w(short* buf, int row, int ku, unsigned v) {
  *(unsigned*)&buf[row * 128 + ((((ku >> 2) ^ (row & 15)) << 3) + ((ku & 3) << 1))] = v;
}
// paired 8B write: requires ku even and (ku&3)<=2 (both 4B slots in one 16B chunk)
__device__ __forceinline__ void stg_w2(short* buf, int row, int ku, unsigned v0, unsigned v1) {
  unsigned long long v = (unsigned long long)v0 | ((unsigned long long)v1 << 32);
  *(unsigned long long*)&buf[row * 128 + ((((ku >> 2) ^ (row & 15)) << 3) + ((ku & 3) << 1))] = v;
}

// ---------------- kernel 0: weight prep f32 [k][n] -> bf16 [n][k] ----------------
__global__ __launch_bounds__(256) void kPrepW(
    const float* __restrict__ w0, const float* __restrict__ w1,
    const float* __restrict__ w2, const float* __restrict__ w3,
    const float* __restrict__ w4, short* __restrict__ wt)
{
  const int wi = blockIdx.y;
  const float* W = wi==0 ? w0 : wi==1 ? w1 : wi==2 ? w2 : wi==3 ? w3 : w4;
  const int e = blockIdx.x * 256 + threadIdx.x;   // 0..16383
  const int k = e >> 7, n = e & 127;              // coalesced read along n
  wt[wi * 16384 + n * 128 + k] = (short)f2b(W[k * CD + n]);
}

// ---------------- kernel 1: LN(z) + 5 projections + gating (5-barrier merge) ----
// 2048 blocks x 1024 thr; block = 128 rows; wave = 16 rows x 64 channels.
// zln triple-duty: LN result -> w_g buffer -> gv stage. All stages in one phase.
__global__ __launch_bounds__(1024, 4) void kProj(
    const float* __restrict__ z, const float* __restrict__ mask,
    const short* __restrict__ wT,
    const float* __restrict__ b_a_p, const float* __restrict__ b_a_g,
    const float* __restrict__ b_b_p, const float* __restrict__ b_b_g,
    const float* __restrict__ b_g,
    const float* __restrict__ ln_s, const float* __restrict__ ln_b,
    short* __restrict__ a_t, short* __restrict__ b_t, short* __restrict__ g_out)
{
  __shared__ short zln[128 * 128];   // LN result; w_g after B2; gv stage after B4
  __shared__ short sS[128 * 128];    // av/bv [128 ch][128 rows]
  __shared__ short wA[128 * 128];    // gate-weight buffer
  __shared__ short wB[128 * 128];    // product-weight buffer
  const int t = threadIdx.x;
  const int r0 = blockIdx.x * 128;
  const int w = t >> 6, l = t & 63, lr = l & 15, lg = l >> 4;
  const int wr = (w >> 1) * 16;      // wave row base within block (0..112)
  const int hc = (w & 1) * 64;       // wave channel-half base

#define STAGE2(BUF, SLOT) do { _Pragma("unroll") for (int i_=0;i_<2;++i_) {  \
    int U_ = i_*1024 + t; int row_ = U_ >> 4, u_ = U_ & 15;                  \
    gl_lds16(wT + (SLOT)*16384 + row_*128 + ((u_^(row_&15))<<3), (BUF)+U_*8); } } while(0)

  STAGE2(wA, 1);                                  // w_a_g
  STAGE2(wB, 0);                                  // w_a_p

  // ---- LN: 8 threads/row, 16 f32 each, 128 rows ----
  {
    const int row = t >> 3, q = t & 7;
    const float* zp = z + (size_t)(r0 + row) * CD + q * 16;
    float x[16];
#pragma unroll
    for (int i = 0; i < 4; ++i) {
      float4v v = *(const float4v*)(zp + i * 4);
#pragma unroll
      for (int e = 0; e < 4; ++e) x[i*4+e] = v[e];
    }
    float s = 0.f;
#pragma unroll
    for (int i = 0; i < 16; ++i) s += x[i];
    s += __shfl_xor(s, 1, 64);
    s += __shfl_xor(s, 2, 64);
    s += __shfl_xor(s, 4, 64);
    const float mu = s * (1.f/128.f);
    float vs = 0.f;
#pragma unroll
    for (int i = 0; i < 16; ++i) { float d = x[i]-mu; vs += d*d; }
    vs += __shfl_xor(vs, 1, 64);
    vs += __shfl_xor(vs, 2, 64);
    vs += __shfl_xor(vs, 4, 64);
    const float rstd = rsqrtf(vs * (1.f/128.f) + 1e-5f);
#pragma unroll
    for (int i = 0; i < 16; i += 4) {             // paired 8B LDS stores
      int c = q*16 + i;
      float y0 = (x[i]  -mu)*rstd*ln_s[c]   + ln_b[c];
      float y1 = (x[i+1]-mu)*rstd*ln_s[c+1] + ln_b[c+1];
      float y2 = (x[i+2]-mu)*rstd*ln_s[c+2] + ln_b[c+2];
      float y3 = (x[i+3]-mu)*rstd*ln_s[c+3] + ln_b[c+3];
      int addr = row*128 + (((c>>3) ^ (row & 15)) << 3) + (c & 7);
      unsigned long long pv = (unsigned long long)pk2(y0, y1)
                            | ((unsigned long long)pk2(y2, y3) << 32);
      *(unsigned long long*)(&zln[addr]) = pv;
    }
  }

  float bga[4], bpa[4], bgb[4], bpb[4];
#pragma unroll
  for (int cf = 0; cf < 4; ++cf) {
    int ci = hc + cf*16 + lr;
    bga[cf] = b_a_g[ci]; bpa[cf] = b_a_p[ci];
    bgb[cf] = b_b_g[ci]; bpb[cf] = b_b_p[ci];
  }
  float mrow[4];
#pragma unroll
  for (int jj = 0; jj < 4; ++jj) mrow[jj] = mask[r0 + wr + lg*4 + jj];

  __syncthreads();                                // B1: zln + wA + wB ready

  short8 af[4];
#pragma unroll
  for (int ks = 0; ks < 4; ++ks)
    af[ks] = fragr(zln, wr + lr, ks*4 + lg);

  float4v accG[4], accB[4];
  float sg[4][4];

#define ZERO4(A) do { _Pragma("unroll") for (int c_=0;c_<4;++c_) A[c_] = (float4v){0.f,0.f,0.f,0.f}; } while(0)

  // 16-MFMA pass: acc[cf] += af[ks] x BUF[hc+cf*16+lr]  (D: row=z-row, col=channel)
#define WP(ACC, BUF) do { ZERO4(ACC);                                      \
  _Pragma("unroll") for (int ks_=0; ks_<4; ++ks_)                          \
    _Pragma("unroll") for (int cf_=0; cf_<4; ++cf_) {                      \
      short8 wf_ = fragr(BUF, hc + cf_*16 + lr, ks_*4 + lg);               \
      ACC[cf_] = mfma16(af[ks_], wf_, ACC[cf_]);                           \
    } } while(0)

#define SIG4(BG) do { _Pragma("unroll") for (int cf_=0;cf_<4;++cf_)        \
    _Pragma("unroll") for (int j_=0;j_<4;++j_)                             \
      sg[cf_][j_] = sigmoidf_(accG[cf_][j_] + BG[cf_]) * mrow[j_]; } while(0)

  // pack sg*(accB+bias) -> sS ch-major (one 8B write per cf)
#define PKAB(BP) do { _Pragma("unroll") for (int cf_=0;cf_<4;++cf_) {      \
    float v0_ = sg[cf_][0]*(accB[cf_][0]+BP[cf_]);                         \
    float v1_ = sg[cf_][1]*(accB[cf_][1]+BP[cf_]);                         \
    float v2_ = sg[cf_][2]*(accB[cf_][2]+BP[cf_]);                         \
    float v3_ = sg[cf_][3]*(accB[cf_][3]+BP[cf_]);                         \
    int ch_ = hc + cf_*16 + lr, ku_ = (wr >> 1) + lg*2;                    \
    stg_w2(sS, ch_, ku_, pk2(v0_, v1_), pk2(v2_, v3_)); } } while(0)

  // full-sector store of sS [128 ch][128 rows] to DST[ch][r0..r0+128): 32B/thread
#define STORE64A(DST) do { int ch_ = t >> 3;                               \
  _Pragma("unroll") for (int i_=0;i_<2;++i_) {                             \
    int cL_ = (t & 7)*2 + i_;                                              \
    *(short8*)(DST + (size_t)ch_*NN + r0 + cL_*8) = fragr(sS, ch_, cL_);   \
  } } while(0)

  // S1: both a-projections
  WP(accG, wA);                                   // a_g
  WP(accB, wB);                                   // a_p
  SIG4(bga);
  PKAB(bpa);                                      // av -> sS
  __syncthreads();                                // B2: S1 done; af reads drained -> zln free

  // S2: all remaining weight stages + store a (one merged phase)
  STAGE2(wA, 3);                                  // w_b_g
  STAGE2(wB, 2);                                  // w_b_p
  STAGE2(zln, 4);                                 // w_g -> zln
  STORE64A(a_t);
  __syncthreads();                                // B3: stages drained; sS reads done

  // S3: b-projections + gate projection (48 MFMA, one phase)
  WP(accG, wA);                                   // b_g
  WP(accB, wB);                                   // b_p
  float4v accG2[4];
  ZERO4(accG2);
#pragma unroll
  for (int ks = 0; ks < 4; ++ks)
#pragma unroll
    for (int cf = 0; cf < 4; ++cf) {              // swapped: D row=channel, col=z-row
      short8 wf = fragr(zln, hc + cf*16 + lr, ks*4 + lg);
      accG2[cf] = mfma16(wf, af[ks], accG2[cf]);
    }
  SIG4(bgb);
  PKAB(bpb);                                      // bv -> sS
  __syncthreads();                                // B4: bv ready; zln(w_g) reads done

  // S4: store b + pack gv -> zln (row-major)
  STORE64A(b_t);
#pragma unroll
  for (int cf = 0; cf < 4; ++cf) {
    float4v bgv = *(const float4v*)(b_g + hc + cf*16 + lg*4);
    float v0 = sigmoidf_(accG2[cf][0] + bgv[0]);
    float v1 = sigmoidf_(accG2[cf][1] + bgv[1]);
    float v2 = sigmoidf_(accG2[cf][2] + bgv[2]);
    float v3 = sigmoidf_(accG2[cf][3] + bgv[3]);
    int row = wr + lr, ku = (hc >> 1) + cf*8 + lg*2;
    stg_w2(zln, row, ku, pk2(v0, v1), pk2(v2, v3));
  }
  __syncthreads();                                // B5: gv ready

  // S5: store g (row-major, 256B contiguous per row)
  {
    int row = t >> 3;
#pragma unroll
    for (int i = 0; i < 2; ++i) {
      int cL = (t & 7)*2 + i;
      *(short8*)(g_out + (size_t)(r0 + row)*CD + cL*8) = fragr(zln, row, cL);
    }
  }
}

// ---------------- kernel 2: per-channel einsum GEMM X_c = A_c * B_c^T ----------------
// Counted-vmcnt pipeline (r11, proven-correct).
__global__ __launch_bounds__(256, 2) void kEinsum(const short* __restrict__ a_t,
                                                  const short* __restrict__ b_t,
                                                  short* __restrict__ x_t)
{
  __shared__ short As[2][128 * 64];
  __shared__ short Bs[2][128 * 64];
  const int t = threadIdx.x;
  const int d = blockIdx.x;
  const int c = (d & 7) * 16 + (d >> 7);          // channel -> XCD grouping
  const int tile = (d >> 3) & 15;
  const int i0 = (tile >> 2) * 128;
  const int j0 = (tile & 3) * 128;
  const size_t abase = (size_t)c * NN;
  const int w = t >> 6, l = t & 63, lr = l & 15, lg = l >> 4;
  const int wr = w >> 1, wc = w & 1;

  const short* gA[4]; const short* gB[4]; int ldsU[4];
#pragma unroll
  for (int q = 0; q < 4; ++q) {
    int U = q * 256 + t;
    int row = U >> 3, u = U & 7;
    int swz = ((u ^ (row & 7)) << 3);
    gA[q] = a_t + abase + (size_t)(i0 + row) * NDIM + swz;
    gB[q] = b_t + abase + (size_t)(j0 + row) * NDIM + swz;
    ldsU[q] = U * 8;
  }

#define STAGE_E(buf, k0) do { _Pragma("unroll") for (int q_=0;q_<4;++q_) { \
    gl_lds16(gA[q_] + (k0), &As[buf][ldsU[q_]]);                           \
    gl_lds16(gB[q_] + (k0), &Bs[buf][ldsU[q_]]); } } while(0)

  float4v acc[4][4];
#pragma unroll
  for (int m = 0; m < 4; ++m)
#pragma unroll
    for (int n = 0; n < 4; ++n) acc[m][n] = (float4v){0.f,0.f,0.f,0.f};

  STAGE_E(0, 0);                                  // tile 0 -> buf 0
  STAGE_E(1, 64);                                 // tile 1 -> buf 1 (16 in flight)
#pragma unroll
  for (int it = 0; it < 8; ++it) {
    if (it < 7) asm volatile("s_waitcnt vmcnt(8)" ::: "memory");
    else        asm volatile("s_waitcnt vmcnt(0)" ::: "memory");
    __builtin_amdgcn_sched_barrier(0);
    __builtin_amdgcn_s_barrier();                 // all waves: buf[it&1] complete
    const short* Ab = &As[it & 1][0];
    const short* Bb = &Bs[it & 1][0];
    short8 afr[4][2], bfr[4][2];
#pragma unroll
    for (int m = 0; m < 4; ++m)
#pragma unroll
      for (int ks = 0; ks < 2; ++ks) {
        int row = wr*64 + m*16 + lr, j = ks*4 + lg;
        afr[m][ks] = *(const short8*)(Ab + row*64 + ((j ^ (row & 7)) << 3));
      }
#pragma unroll
    for (int n = 0; n < 4; ++n)
#pragma unroll
      for (int ks = 0; ks < 2; ++ks) {
        int row = wc*64 + n*16 + lr, j = ks*4 + lg;
        bfr[n][ks] = *(const short8*)(Bb + row*64 + ((j ^ (row & 7)) << 3));
      }
    __builtin_amdgcn_s_setprio(1);
#pragma unroll
    for (int ks = 0; ks < 2; ++ks)
#pragma unroll
      for (int m = 0; m < 4; ++m)
#pragma unroll
        for (int n = 0; n < 4; ++n)   // swapped: D = (j, i)
          acc[m][n] = mfma16(bfr[n][ks], afr[m][ks], acc[m][n]);
    __builtin_amdgcn_s_setprio(0);
    __builtin_amdgcn_s_barrier();                 // all waves done reading buf[it&1]
    __builtin_amdgcn_sched_barrier(0);
    if (it < 6) STAGE_E(it & 1, (it + 2) * 64);   // refill freed buffer
  }
  // epilogue: stage x-tile into As region (swizzled), then 128B/thread stores
  short* Xs = &As[0][0];                          // 128 x 128 shorts = 32KB
#pragma unroll
  for (int m = 0; m < 4; ++m)
#pragma unroll
    for (int n = 0; n < 4; ++n) {
      int il = wr*64 + m*16 + lr;
      int ku = wc*32 + n*8 + lg*2;
      stg_w2(Xs, il, ku, pk2(acc[m][n][0], acc[m][n][1]),
                         pk2(acc[m][n][2], acc[m][n][3]));
    }
  __syncthreads();
#pragma unroll
  for (int i = 0; i < 8; ++i) {
    int il = t >> 1, cL = (t & 1)*8 + i;
    *(short8*)(x_t + abase + (size_t)(i0 + il)*NDIM + j0 + cL*8) = fragr(Xs, il, cL);
  }
}

// ---------------- kernel 3: LN(x) + x@w_z + b_z, * gate (v2) ----------------
// 2048 blocks x 1024 thr; block = 128 rows; wave = 16 rows x 64 channels.
__global__ __launch_bounds__(1024, 4) void kOut(
    const short* __restrict__ x_t, const short* __restrict__ g_in,
    const float* __restrict__ w_z, const float* __restrict__ b_z,
    const float* __restrict__ ln_s, const float* __restrict__ ln_b,
    float* __restrict__ out)
{
  __shared__ short xs[128 * 128];   // gathered x [ch][rows], swizzle key (ch>>3)&15; sG after s2
  __shared__ short xln[128 * 128];  // LN result, swizzle key row&15
  __shared__ short sW[128 * 128];   // w_z bf16 [n][k], swizzle key row&15
  const int t = threadIdx.x;
  const int r0 = blockIdx.x * 128;
  const int w = t >> 6, l = t & 63, lr = l & 15, lg = l >> 4;
  const int rowb = (w >> 1) * 16;   // wave row base
  const int hc = (w & 1) * 64;      // wave channel-half base

  // A) early gate loads -> regs (coalesced 16B/lane)
  short8 gv[2];
#pragma unroll
  for (int v = 0; v < 2; ++v) {
    int V = v*1024 + t; int row = V >> 4, u = V & 15;
    gv[v] = *(const short8*)(g_in + (size_t)(r0 + row) * CD + u * 8);
  }
  // B) gather x columns -> xs via gl_lds (pre-swizzled source, key (cc>>3)&15)
#pragma unroll
  for (int v = 0; v < 2; ++v) {
    int U = v*1024 + t; int cc = U >> 4, u = U & 15;
    gl_lds16(x_t + (size_t)cc * NN + r0 + ((u ^ ((cc >> 3) & 15)) << 3), xs + U*8);
  }
  // C) stage w_z f32 [k][n] -> swizzled bf16 [n][k]
#pragma unroll
  for (int i = 0; i < 2; ++i) {
    int flat = i*1024 + t;
    int kp = flat >> 5, k = kp * 2, n4 = (flat & 31) * 4;
    float4v va = *(const float4v*)(w_z + (size_t)k * CD + n4);
    float4v vb = *(const float4v*)(w_z + (size_t)(k + 1) * CD + n4);
#pragma unroll
    for (int j = 0; j < 4; ++j) {
      int row = n4 + j;
      int addr = row * 128 + (((k >> 3) ^ (row & 15)) << 3) + (k & 7);
      *(unsigned*)(&sW[addr]) = pk2(va[j], vb[j]);
    }
  }
  __syncthreads();                                // s1: xs + sW ready
  // D) LN over channels: 8 thr/row, 16 ch each
  {
    const int r = t >> 3, q = t & 7;
    float x[16];
#pragma unroll
    for (int i = 0; i < 16; ++i) {
      int c = q*16 + i;
      x[i] = b2f((unsigned short)xs[c*128 + (((r >> 3) ^ ((c >> 3) & 15)) << 3) + (r & 7)]);
    }
    float s = 0.f;
#pragma unroll
    for (int i = 0; i < 16; ++i) s += x[i];
    s += __shfl_xor(s, 1, 64);
    s += __shfl_xor(s, 2, 64);
    s += __shfl_xor(s, 4, 64);
    const float mu = s * (1.f/128.f);
    float vs = 0.f;
#pragma unroll
    for (int i = 0; i < 16; ++i) { float d = x[i]-mu; vs += d*d; }
    vs += __shfl_xor(vs, 1, 64);
    vs += __shfl_xor(vs, 2, 64);
    vs += __shfl_xor(vs, 4, 64);
    const float rstd = rsqrtf(vs * (1.f/128.f) + 1e-5f);
#pragma unroll
    for (int i = 0; i < 16; i += 4) {             // paired 8B LDS stores
      int c = q*16 + i;
      float y0 = (x[i]  -mu)*rstd*ln_s[c]   + ln_b[c];
      float y1 = (x[i+1]-mu)*rstd*ln_s[c+1] + ln_b[c+1];
      float y2 = (x[i+2]-mu)*rstd*ln_s[c+2] + ln_b[c+2];
      float y3 = (x[i+3]-mu)*rstd*ln_s[c+3] + ln_b[c+3];
      int addr = r*128 + (((c>>3) ^ (r & 15)) << 3) + (c & 7);
      unsigned long long pv = (unsigned long long)pk2(y0, y1)
                            | ((unsigned long long)pk2(y2, y3) << 32);
      *(unsigned long long*)(&xln[addr]) = pv;
    }
  }
  __syncthreads();                                // s2: xln ready; xs dead
  // E) gate -> sG (xs region); fragments; MFMA (unswapped: D row=z-row, col=ch)
  short* sG = xs;
#pragma unroll
  for (int v = 0; v < 2; ++v) {
    int V = v*1024 + t; int row = V >> 4, u = V & 15;
    *(short8*)(sG + row*128 + ((u ^ (row & 15)) << 3)) = gv[v];
  }
  short8 af[4];
#pragma unroll
  for (int ks = 0; ks < 4; ++ks)
    af[ks] = fragr(xln, rowb + lr, ks*4 + lg);
  float4v acc[4];
#pragma unroll
  for (int cf = 0; cf < 4; ++cf) acc[cf] = (float4v){0.f,0.f,0.f,0.f};
#pragma unroll
  for (int ks = 0; ks < 4; ++ks)
#pragma unroll
    for (int cf = 0; cf < 4; ++cf) {
      short8 wf = fragr(sW, hc + cf*16 + lr, ks*4 + lg);
      acc[cf] = mfma16(af[ks], wf, acc[cf]);
    }
  float bz[4];
#pragma unroll
  for (int cf = 0; cf < 4; ++cf) bz[cf] = b_z[hc + cf*16 + lr];
  __syncthreads();                                // s3: sG ready
  // F) gated output, direct full-sector stores (16 lanes x 4B = 64B per (cf,jj))
#pragma unroll
  for (int cf = 0; cf < 4; ++cf) {
    int ch = hc + cf*16 + lr;
#pragma unroll
    for (int jj = 0; jj < 4; ++jj) {
      int row = rowb + lg*4 + jj;
      float gvv = b2f((unsigned short)sG[row*128 + (((ch>>3) ^ (row & 15)) << 3) + (ch & 7)]);
      out[(size_t)(r0 + row) * CD + ch] = (acc[cf][jj] + bz[cf]) * gvv;
    }
  }
}

extern "C" void kernel_launch(void* const* d_in, const int* in_sizes, int n_in,
                              void* d_out, int out_size, void* d_ws, size_t ws_size,
                              hipStream_t stream) {
  (void)in_sizes; (void)n_in; (void)out_size; (void)ws_size;
  const float* z     = (const float*)d_in[0];
  const float* mask  = (const float*)d_in[1];
  const float* w_a_p = (const float*)d_in[2];
  const float* b_a_p = (const float*)d_in[3];
  const float* w_a_g = (const float*)d_in[4];
  const float* b_a_g = (const float*)d_in[5];
  const float* w_b_p = (const float*)d_in[6];
  const float* b_b_p = (const float*)d_in[7];
  const float* w_b_g = (const float*)d_in[8];
  const float* b_b_g = (const float*)d_in[9];
  const float* w_g   = (const float*)d_in[10];
  const float* b_g   = (const float*)d_in[11];
  const float* w_z   = (const float*)d_in[12];
  const float* b_z   = (const float*)d_in[13];
  const float* ln_i_s = (const float*)d_in[14];
  const float* ln_i_b = (const float*)d_in[15];
  const float* ln_o_s = (const float*)d_in[16];
  const float* ln_o_b = (const float*)d_in[17];

  short* a_t = (short*)d_ws;
  short* b_t = a_t + (size_t)CD*NN;
  short* g_s = b_t + (size_t)CD*NN;
  short* x_t = g_s + (size_t)CD*NN;
  short* wT  = x_t;                                // 160 KB at head of x_t (kProj only)

  hipLaunchKernelGGL(kPrepW, dim3(64, 5), dim3(256), 0, stream,
                     w_a_p, w_a_g, w_b_p, w_b_g, w_g, wT);
  hipLaunchKernelGGL(kProj, dim3(NN/128), dim3(1024), 0, stream,
                     z, mask, wT, b_a_p, b_a_g, b_b_p, b_b_g, b_g,
                     ln_i_s, ln_i_b, a_t, b_t, g_s);
  hipLaunchKernelGGL(kEinsum, dim3(2048), dim3(256), 0, stream, a_t, b_t, x_t);
  hipLaunchKernelGGL(kOut, dim3(NN/128), dim3(1024), 0, stream,
                     x_t, g_s, w_z, b_z, ln_o_s, ln_o_b, (float*)d_out);
}